// Round 3
// baseline (833.272 us; speedup 1.0000x reference)
//
#include <hip/hip_runtime.h>
#include <hip/hip_bf16.h>

// ---------------------------------------------------------------------------
// MoE dense all-expert forward, MI355X / gfx950.  B=16384, D=H=O=256, E=32.
// Round 7: 32x32x16 MFMA + launch-bounds fix.
//  - __launch_bounds__(1024, 1): second arg is min BLOCKS/CU (CUDA semantics,
//    confirmed empirically: (1024,4) capped VGPRs at 64 -> 1.4 GB spill).
//    1 block/CU -> 4 waves/SIMD -> 128-VGPR budget, no spills at ~110 live.
//  - mfma_f32_32x32x16_bf16: 32 KFLOP per 1 KB LDS B-frag (2x the FLOP/LDS
//    byte of 16x16x32) -> LDS read traffic per CU halves to ~17 MB, below
//    the MFMA floor. Wave tile = 32 cols x 32 rows (cg 0..7, rg 0..1).
//  - merged-role waves: every wave does GEMM1(e) and GEMM2(e-1), fused per
//    k-step; weight A-frags register-streamed (depth-4 rings, prefetch +4).
//  - h_s double-buffered, ONE raw s_barrier per phase, lgkmcnt-only drain
//    (weight prefetches stay in flight across the barrier).
// ---------------------------------------------------------------------------

typedef __attribute__((ext_vector_type(8))) short bf16x8;   // 8 bf16 = 4 VGPRs
typedef __attribute__((ext_vector_type(4))) float f32x4;
typedef __attribute__((ext_vector_type(16))) float f32x16;  // 32x32 C frag

__device__ __forceinline__ unsigned short f2bf(float f) {
    unsigned u = __builtin_bit_cast(unsigned, f);
    u += 0x7FFFu + ((u >> 16) & 1u);        // round-to-nearest-even
    return (unsigned short)(u >> 16);
}
__device__ __forceinline__ unsigned pack_bf16x2(float a, float b) {
    return (unsigned)f2bf(a) | ((unsigned)f2bf(b) << 16);
}

// 16B-chunk XOR swizzle for [64 rows][256 elem] bf16 tiles (index in ushorts)
#define LX(r, ch) (((r) << 8) + ((((ch) ^ ((r) & 7))) << 3))

// ------------------- W f32 -> bf16 convert + tile reorder ------------------
// Stream (m, cg): m=0 -> W1 rows cg*32..+31, m=1 -> W2 rows cg*32..+31.
// Per stream: 33 experts (e=32 is prefetch-overrun pad) x 16 k-step chunks.
// Chunk = 512 bf16 = 1 KB, element (lane, j): row = cg*32 + (lane&31),
// k = ks*16 + (lane>>5)*8 + j  — the mfma_32x32x16 A-frag order.
__global__ __launch_bounds__(256) void cvt_w(const float* __restrict__ W1,
                                             const float* __restrict__ W2,
                                             unsigned short* __restrict__ Wr) {
    int T = blockIdx.x * 256 + threadIdx.x;          // 524288 threads
    int lane = T & 63, ks = (T >> 6) & 15, e = (T >> 10) & 31;
    int cg = (T >> 15) & 7, m = (T >> 18) & 1;
    int l31 = lane & 31, hi = lane >> 5;
    const float* src = (m ? W2 : W1) +
                       ((long)e * 256 + cg * 32 + l31) * 256 + ks * 16 + hi * 8;
    float4 v0 = ((const float4*)src)[0], v1 = ((const float4*)src)[1];
    uint4 o;
    o.x = pack_bf16x2(v0.x, v0.y); o.y = pack_bf16x2(v0.z, v0.w);
    o.z = pack_bf16x2(v1.x, v1.y); o.w = pack_bf16x2(v1.z, v1.w);
    long U = (((long)(m * 8 + cg) * 33 + e) * 16 + ks) * 64 + lane;
    ((uint4*)Wr)[U] = o;
}

// ------------------------------ fused MoE ----------------------------------
// One GEMM1 k-step: consume W1 ring slot, refill 4 chunks ahead, 1 MFMA.
#define G1STEP(ks) do {                                                        \
    bf16x8 a = r1[(ks) & 3];                                                   \
    r1[(ks) & 3] = *(const bf16x8*)(w1p + (e * 16 + (ks) + 4) * 512);          \
    bf16x8 xb = *(const bf16x8*)(&x_s[LX(rl0 + l31, (ks) * 2 + hi)]);          \
    __builtin_amdgcn_s_setprio(1);                                             \
    hacc = __builtin_amdgcn_mfma_f32_32x32x16_bf16(a, xb, hacc, 0, 0, 0);      \
    __builtin_amdgcn_s_setprio(0);                                             \
} while (0)

// One GEMM2 k-step: consume W2 ring slot, refill, 1 MFMA from h_s[(e-1)&1].
#define G2STEP(ks) do {                                                        \
    bf16x8 a = r2[(ks) & 3];                                                   \
    r2[(ks) & 3] = *(const bf16x8*)(w2p + (me * 16 + (ks) + 4) * 512);         \
    bf16x8 hb = *(const bf16x8*)(&hbr[LX(rl0 + l31, (ks) * 2 + hi)]);          \
    __builtin_amdgcn_s_setprio(1);                                             \
    oacc = __builtin_amdgcn_mfma_f32_32x32x16_bf16(a, hb, oacc, 0, 0, 0);      \
    __builtin_amdgcn_s_setprio(0);                                             \
} while (0)

__global__ __launch_bounds__(1024, 1) void moe_kernel(
    const float* __restrict__ x,
    const unsigned short* __restrict__ Wr,
    const float* __restrict__ bias1,
    const float* __restrict__ b2,
    const float* __restrict__ Wg,
    const float* __restrict__ bg,
    float* __restrict__ out)
{
    __shared__ __align__(16) unsigned short x_s[64 * 256];      // 32 KB
    __shared__ __align__(16) unsigned short h_s[2][64 * 256];   // 64 KB dbuf
    __shared__ float gws[64 * 33];                              // gate weights

    const int tid  = threadIdx.x;
    const int wv   = tid >> 6, lane = tid & 63;
    const int l31  = lane & 31, hi = lane >> 5;
    const int cg   = wv & 7;                    // 32-col group (h / out cols)
    const int rl0  = (wv >> 3) * 32;            // 32-row group (batch rows)
    const int row0 = blockIdx.x * 64;

    // ---- stage x tile: f32 global -> bf16 LDS (swizzled) ----
#pragma unroll
    for (int c = 0; c < 2; ++c) {
        int chunk = tid + c * 1024;             // 2048 chunks of 8 elems
        int r = chunk >> 5, ch = chunk & 31;
        const float4* s = (const float4*)(x + (long)(row0 + r) * 256 + ch * 8);
        float4 v0 = s[0], v1 = s[1];
        uint4 o;
        o.x = pack_bf16x2(v0.x, v0.y); o.y = pack_bf16x2(v0.z, v0.w);
        o.z = pack_bf16x2(v1.x, v1.y); o.w = pack_bf16x2(v1.z, v1.w);
        *(uint4*)(&x_s[LX(r, ch)]) = o;
    }

    // ---- inline gating: 4 rows per wave, all f32 (matches reference) ----
    {
        const int e32 = lane & 31, half = lane >> 5;
        const float4* wg4 = (const float4*)(Wg + e32 * 256 + half * 128);
        float bgv = bg[e32];
        for (int i = 0; i < 4; ++i) {
            int lr = wv * 4 + i;
            const float4* xr4 = (const float4*)(x + (long)(row0 + lr) * 256 + half * 128);
            float acc = 0.f;
#pragma unroll
            for (int tt = 0; tt < 32; ++tt) {
                float4 w = wg4[tt], xv = xr4[tt];
                acc = fmaf(w.x, xv.x, acc); acc = fmaf(w.y, xv.y, acc);
                acc = fmaf(w.z, xv.z, acc); acc = fmaf(w.w, xv.w, acc);
            }
            acc += __shfl_xor(acc, 32);
            float score = (acc + bgv) / 2.71828182845904523f;   // TEMP = e

            float m = score;
#pragma unroll
            for (int d = 16; d >= 1; d >>= 1) m = fmaxf(m, __shfl_xor(m, d));
            float p = expf(score - m);
            float ps = p;
#pragma unroll
            for (int d = 16; d >= 1; d >>= 1) ps += __shfl_xor(ps, d);
            float prob = p / ps;

            int rank = 0;
#pragma unroll
            for (int j = 0; j < 32; ++j) {
                float pj = __shfl(prob, j);
                rank += (pj > prob || (pj == prob && j < e32)) ? 1 : 0;
            }
            float kept = (rank < 22) ? prob : 0.f;
            float wsum = kept;
#pragma unroll
            for (int d = 16; d >= 1; d >>= 1) wsum += __shfl_xor(wsum, d);
            float weight = kept / (wsum + 1e-8f);

            if (half == 0) gws[lr * 33 + e32] = weight;
        }
    }

    __syncthreads();   // x_s + gws ready

    // ---- weight stream bases + depth-4 register ring preload ----
    const unsigned short* w1p = Wr + (long)cg * (33 * 16 * 512) + lane * 8;
    const unsigned short* w2p = Wr + (long)(8 + cg) * (33 * 16 * 512) + lane * 8;
    bf16x8 r1[4], r2[4];
#pragma unroll
    for (int t = 0; t < 4; ++t) {
        r1[t] = *(const bf16x8*)(w1p + t * 512);
        r2[t] = *(const bf16x8*)(w2p + t * 512);
    }

    // ---- oacc init = sum_e gw * b2 (in-register bias2 combine) ----
    // C frag: batch col = lane&31, out-col = (reg&3) + 8*(reg>>2) + 4*hi
    f32x16 oacc;
#pragma unroll
    for (int i = 0; i < 16; ++i) oacc[i] = 0.f;
    {
        float gv;
        for (int ee = 0; ee < 32; ++ee) {
            gv = gws[(rl0 + l31) * 33 + ee];
#pragma unroll
            for (int q = 0; q < 4; ++q) {
                float4 bb = *(const float4*)(b2 + ee * 256 + cg * 32 + q * 8 + hi * 4);
                oacc[4 * q + 0] = fmaf(gv, bb.x, oacc[4 * q + 0]);
                oacc[4 * q + 1] = fmaf(gv, bb.y, oacc[4 * q + 1]);
                oacc[4 * q + 2] = fmaf(gv, bb.z, oacc[4 * q + 2]);
                oacc[4 * q + 3] = fmaf(gv, bb.w, oacc[4 * q + 3]);
            }
        }
    }

    // ---- expert pipeline: per phase e, GEMM1(e) + GEMM2(e-1) fused ----
    for (int e = 0; e <= 32; ++e) {
        f32x16 hacc;
#pragma unroll
        for (int i = 0; i < 16; ++i) hacc[i] = 0.f;
        const int me = e - 1;
        const unsigned short* hbr = h_s[(e + 1) & 1];   // == h_s[(e-1)&1]

        if (e == 0) {
#pragma unroll
            for (int ks = 0; ks < 16; ++ks) G1STEP(ks);
        } else if (e < 32) {
#pragma unroll
            for (int ks = 0; ks < 16; ++ks) { G1STEP(ks); G2STEP(ks); }
        } else {
#pragma unroll
            for (int ks = 0; ks < 16; ++ks) G2STEP(ks);
        }

        // epilogue: +b1, relu, * gate weight, packed 8B -> h_s[e&1]
        if (e < 32) {
            unsigned short* hw = h_s[e & 1];
            const int rr = rl0 + l31;
            const float gw = gws[rr * 33 + e];
            const int rbase = rr << 8, rsw = rr & 7;
#pragma unroll
            for (int q = 0; q < 4; ++q) {
                float4 bv = *(const float4*)(bias1 + e * 256 + cg * 32 + q * 8 + hi * 4);
                float v0 = fmaxf(hacc[4 * q + 0] + bv.x, 0.f) * gw;
                float v1 = fmaxf(hacc[4 * q + 1] + bv.y, 0.f) * gw;
                float v2 = fmaxf(hacc[4 * q + 2] + bv.z, 0.f) * gw;
                float v3 = fmaxf(hacc[4 * q + 3] + bv.w, 0.f) * gw;
                uint2 pk;
                pk.x = pack_bf16x2(v0, v1);
                pk.y = pack_bf16x2(v2, v3);
                *(uint2*)(&hw[rbase + (((cg * 4 + q) ^ rsw) << 3) + hi * 4]) = pk;
            }
        }

        // barrier with LDS-only drain: weight prefetches stay in flight
        asm volatile("s_waitcnt lgkmcnt(0)" ::: "memory");
        __builtin_amdgcn_s_barrier();
    }

    // ---- final store: out C frags -> out[batch][outcol] ----
#pragma unroll
    for (int q = 0; q < 4; ++q) {
        f32x4 st = {oacc[4 * q + 0], oacc[4 * q + 1],
                    oacc[4 * q + 2], oacc[4 * q + 3]};
        *(f32x4*)(out + (long)(row0 + rl0 + l31) * 256 +
                  cg * 32 + q * 8 + hi * 4) = st;
    }
}

// ------------------------------- launch ------------------------------------
extern "C" void kernel_launch(void* const* d_in, const int* in_sizes, int n_in,
                              void* d_out, int out_size, void* d_ws, size_t ws_size,
                              hipStream_t stream) {
    (void)in_sizes; (void)n_in; (void)out_size; (void)ws_size;
    const float* x  = (const float*)d_in[0];   // [16384,256]
    const float* W1 = (const float*)d_in[1];   // [32,256,256]
    const float* b1 = (const float*)d_in[2];   // [32,256]
    const float* W2 = (const float*)d_in[3];   // [32,256,256]
    const float* b2 = (const float*)d_in[4];   // [32,256]
    const float* Wg = (const float*)d_in[5];   // [32,256]
    const float* bg = (const float*)d_in[6];   // [32]
    float* out = (float*)d_out;                // [16384,256]

    // ws: Wr = 16 streams x 33 experts x 16 KB = 8.25 MiB (expert 32 = pad)
    unsigned short* Wr = (unsigned short*)d_ws;

    cvt_w<<<2048, 256, 0, stream>>>(W1, W2, Wr);
    moe_kernel<<<256, 1024, 0, stream>>>(x, Wr, b1, b2, Wg, bg, out);
}

// Round 4
// 735.052 us; speedup vs baseline: 1.1336x; 1.1336x over previous
//
#include <hip/hip_runtime.h>
#include <hip/hip_bf16.h>

// ---------------------------------------------------------------------------
// MoE dense all-expert forward, MI355X / gfx950.  B=16384, D=H=O=256, E=32.
// Round 8: back to 512-thread blocks (register-budget fix) + 32x32 MFMA.
//  LESSON (R1/R2): a 1024-thread workgroup forces 4 waves/SIMD residency ->
//  <=128 unified VGPR+AGPR/wave (observed: 64 arch VGPR + spills, 1.4-2 GB
//  scratch traffic). Deep register pipelines need 512-thread blocks
//  (8 waves -> 2/SIMD -> 256-reg budget; R0 measured 112 VGPR, no spill).
//  - 256 blocks x 512 thr, 1 block/CU. Wave = 64 out-cols x 32 rows
//    (2 col-groups share one B-frag ds_read -> 0.5 KB LDS / 32KFLOP MFMA;
//    LDS floor ~31 us < MFMA floor ~58 us).
//  - merged-role waves: GEMM1(e) and GEMM2(e-1) fused per k-step.
//  - 4 weight streams/wave, register rings depth 4 (prefetch 4 k-steps
//    ~600 cyc ahead -> covers L2/L3 latency; R0 stalled at depth 1).
//  - h_s double-buffered, ONE raw s_barrier per phase, lgkmcnt-only drain
//    (global weight prefetches stay in flight across the barrier).
// ---------------------------------------------------------------------------

typedef __attribute__((ext_vector_type(8))) short bf16x8;   // 8 bf16 = 4 VGPRs
typedef __attribute__((ext_vector_type(4))) float f32x4;
typedef __attribute__((ext_vector_type(16))) float f32x16;  // 32x32 C frag

__device__ __forceinline__ unsigned short f2bf(float f) {
    unsigned u = __builtin_bit_cast(unsigned, f);
    u += 0x7FFFu + ((u >> 16) & 1u);        // round-to-nearest-even
    return (unsigned short)(u >> 16);
}
__device__ __forceinline__ unsigned pack_bf16x2(float a, float b) {
    return (unsigned)f2bf(a) | ((unsigned)f2bf(b) << 16);
}

// 16B-chunk XOR swizzle for [64 rows][256 elem] bf16 tiles (index in ushorts)
#define LX(r, ch) (((r) << 8) + ((((ch) ^ ((r) & 7))) << 3))

// ------------------- W f32 -> bf16 convert + tile reorder ------------------
// Stream s = m*8 + cg: m=0 -> W1 rows cg*32..+31, m=1 -> W2 rows cg*32..+31.
// Per stream: 33 experts (e=32 is prefetch-overrun pad) x 16 k-step chunks.
// Chunk = 512 bf16 = 1 KB, element (lane, j): row = cg*32 + (lane&31),
// k = ks*16 + (lane>>5)*8 + j  — the mfma_32x32x16 A-frag order.
__global__ __launch_bounds__(256) void cvt_w(const float* __restrict__ W1,
                                             const float* __restrict__ W2,
                                             unsigned short* __restrict__ Wr) {
    int T = blockIdx.x * 256 + threadIdx.x;          // 524288 threads
    int lane = T & 63, ks = (T >> 6) & 15, e = (T >> 10) & 31;
    int cg = (T >> 15) & 7, m = (T >> 18) & 1;
    int l31 = lane & 31, hi = lane >> 5;
    const float* src = (m ? W2 : W1) +
                       ((long)e * 256 + cg * 32 + l31) * 256 + ks * 16 + hi * 8;
    float4 v0 = ((const float4*)src)[0], v1 = ((const float4*)src)[1];
    uint4 o;
    o.x = pack_bf16x2(v0.x, v0.y); o.y = pack_bf16x2(v0.z, v0.w);
    o.z = pack_bf16x2(v1.x, v1.y); o.w = pack_bf16x2(v1.z, v1.w);
    long U = (((long)(m * 8 + cg) * 33 + e) * 16 + ks) * 64 + lane;
    ((uint4*)Wr)[U] = o;
}

// ------------------------------ fused MoE ----------------------------------
// One GEMM1 k-step: consume 2 W1 ring slots, refill +4 ahead, 1 shared
// B-frag ds_read, 2 MFMAs.
#define G1STEP(ks) do {                                                        \
    bf16x8 aA = r1a[(ks) & 3], aB = r1b[(ks) & 3];                             \
    r1a[(ks) & 3] = *(const bf16x8*)(w1a + (e * 16 + (ks) + 4) * 512);         \
    r1b[(ks) & 3] = *(const bf16x8*)(w1b + (e * 16 + (ks) + 4) * 512);         \
    bf16x8 xb = *(const bf16x8*)(&x_s[LX(rl0 + l31, (ks) * 2 + hi)]);          \
    __builtin_amdgcn_s_setprio(1);                                             \
    hacc0 = __builtin_amdgcn_mfma_f32_32x32x16_bf16(aA, xb, hacc0, 0, 0, 0);   \
    hacc1 = __builtin_amdgcn_mfma_f32_32x32x16_bf16(aB, xb, hacc1, 0, 0, 0);   \
    __builtin_amdgcn_s_setprio(0);                                             \
} while (0)

// One GEMM2 k-step: consume 2 W2 ring slots, refill, shared B-frag from
// h_s[(e-1)&1], 2 MFMAs.
#define G2STEP(ks) do {                                                        \
    bf16x8 aA = r2a[(ks) & 3], aB = r2b[(ks) & 3];                             \
    r2a[(ks) & 3] = *(const bf16x8*)(w2a + (me * 16 + (ks) + 4) * 512);        \
    r2b[(ks) & 3] = *(const bf16x8*)(w2b + (me * 16 + (ks) + 4) * 512);        \
    bf16x8 hb = *(const bf16x8*)(&hbr[LX(rl0 + l31, (ks) * 2 + hi)]);          \
    __builtin_amdgcn_s_setprio(1);                                             \
    oacc0 = __builtin_amdgcn_mfma_f32_32x32x16_bf16(aA, hb, oacc0, 0, 0, 0);   \
    oacc1 = __builtin_amdgcn_mfma_f32_32x32x16_bf16(aB, hb, oacc1, 0, 0, 0);   \
    __builtin_amdgcn_s_setprio(0);                                             \
} while (0)

__global__ __launch_bounds__(512, 2) void moe_kernel(
    const float* __restrict__ x,
    const unsigned short* __restrict__ Wr,
    const float* __restrict__ bias1,
    const float* __restrict__ b2,
    const float* __restrict__ Wg,
    const float* __restrict__ bg,
    float* __restrict__ out)
{
    __shared__ __align__(16) unsigned short x_s[64 * 256];      // 32 KB
    __shared__ __align__(16) unsigned short h_s[2][64 * 256];   // 64 KB dbuf
    __shared__ float gws[64 * 33];                              // gate weights

    const int tid  = threadIdx.x;
    const int wv   = tid >> 6, lane = tid & 63;
    const int l31  = lane & 31, hi = lane >> 5;
    const int p    = wv & 3;                    // col-pair: cols p*64..p*64+63
    const int rl0  = (wv >> 2) * 32;            // row group: rows rl0..rl0+31
    const int row0 = blockIdx.x * 64;

    // ---- stage x tile: f32 global -> bf16 LDS (swizzled) ----
#pragma unroll
    for (int c = 0; c < 4; ++c) {
        int chunk = tid + c * 512;              // 2048 chunks of 8 elems
        int r = chunk >> 5, ch = chunk & 31;
        const float4* s = (const float4*)(x + (long)(row0 + r) * 256 + ch * 8);
        float4 v0 = s[0], v1 = s[1];
        uint4 o;
        o.x = pack_bf16x2(v0.x, v0.y); o.y = pack_bf16x2(v0.z, v0.w);
        o.z = pack_bf16x2(v1.x, v1.y); o.w = pack_bf16x2(v1.z, v1.w);
        *(uint4*)(&x_s[LX(r, ch)]) = o;
    }

    // ---- inline gating: 8 rows per wave, all f32 (matches reference) ----
    {
        const int e32 = lane & 31, half = lane >> 5;
        const float4* wg4 = (const float4*)(Wg + e32 * 256 + half * 128);
        float bgv = bg[e32];
        for (int i = 0; i < 8; ++i) {
            int lr = wv * 8 + i;
            const float4* xr4 = (const float4*)(x + (long)(row0 + lr) * 256 + half * 128);
            float acc = 0.f;
#pragma unroll
            for (int tt = 0; tt < 32; ++tt) {
                float4 w = wg4[tt], xv = xr4[tt];
                acc = fmaf(w.x, xv.x, acc); acc = fmaf(w.y, xv.y, acc);
                acc = fmaf(w.z, xv.z, acc); acc = fmaf(w.w, xv.w, acc);
            }
            acc += __shfl_xor(acc, 32);
            float score = (acc + bgv) / 2.71828182845904523f;   // TEMP = e

            float m = score;
#pragma unroll
            for (int d = 16; d >= 1; d >>= 1) m = fmaxf(m, __shfl_xor(m, d));
            float p_ = expf(score - m);
            float ps = p_;
#pragma unroll
            for (int d = 16; d >= 1; d >>= 1) ps += __shfl_xor(ps, d);
            float prob = p_ / ps;

            int rank = 0;
#pragma unroll
            for (int j = 0; j < 32; ++j) {
                float pj = __shfl(prob, j);
                rank += (pj > prob || (pj == prob && j < e32)) ? 1 : 0;
            }
            float kept = (rank < 22) ? prob : 0.f;
            float wsum = kept;
#pragma unroll
            for (int d = 16; d >= 1; d >>= 1) wsum += __shfl_xor(wsum, d);
            float weight = kept / (wsum + 1e-8f);

            if (half == 0) gws[lr * 33 + e32] = weight;
        }
    }

    __syncthreads();   // x_s + gws ready

    // ---- weight stream bases (4 streams/wave) + depth-4 ring preload ----
    const unsigned short* w1a = Wr + (long)(2 * p)     * (33 * 16 * 512) + lane * 8;
    const unsigned short* w1b = Wr + (long)(2 * p + 1) * (33 * 16 * 512) + lane * 8;
    const unsigned short* w2a = Wr + (long)(8 + 2 * p)     * (33 * 16 * 512) + lane * 8;
    const unsigned short* w2b = Wr + (long)(8 + 2 * p + 1) * (33 * 16 * 512) + lane * 8;
    bf16x8 r1a[4], r1b[4], r2a[4], r2b[4];
#pragma unroll
    for (int t = 0; t < 4; ++t) {
        r1a[t] = *(const bf16x8*)(w1a + t * 512);
        r1b[t] = *(const bf16x8*)(w1b + t * 512);
        r2a[t] = *(const bf16x8*)(w2a + t * 512);
        r2b[t] = *(const bf16x8*)(w2b + t * 512);
    }

    // ---- oacc init = sum_e gw * b2 (in-register bias2 combine) ----
    // C frag: batch row = lane&31, out-col = (reg&3) + 8*(reg>>2) + 4*hi
    f32x16 oacc0, oacc1;
#pragma unroll
    for (int i = 0; i < 16; ++i) { oacc0[i] = 0.f; oacc1[i] = 0.f; }
    for (int ee = 0; ee < 32; ++ee) {
        float gv = gws[(rl0 + l31) * 33 + ee];
#pragma unroll
        for (int q = 0; q < 4; ++q) {
            float4 ba = *(const float4*)(b2 + ee * 256 + (2 * p) * 32 + q * 8 + hi * 4);
            float4 bb = *(const float4*)(b2 + ee * 256 + (2 * p + 1) * 32 + q * 8 + hi * 4);
            oacc0[4 * q + 0] = fmaf(gv, ba.x, oacc0[4 * q + 0]);
            oacc0[4 * q + 1] = fmaf(gv, ba.y, oacc0[4 * q + 1]);
            oacc0[4 * q + 2] = fmaf(gv, ba.z, oacc0[4 * q + 2]);
            oacc0[4 * q + 3] = fmaf(gv, ba.w, oacc0[4 * q + 3]);
            oacc1[4 * q + 0] = fmaf(gv, bb.x, oacc1[4 * q + 0]);
            oacc1[4 * q + 1] = fmaf(gv, bb.y, oacc1[4 * q + 1]);
            oacc1[4 * q + 2] = fmaf(gv, bb.z, oacc1[4 * q + 2]);
            oacc1[4 * q + 3] = fmaf(gv, bb.w, oacc1[4 * q + 3]);
        }
    }

    // ---- expert pipeline: per phase e, GEMM1(e) + GEMM2(e-1) fused ----
    for (int e = 0; e <= 32; ++e) {
        f32x16 hacc0, hacc1;
#pragma unroll
        for (int i = 0; i < 16; ++i) { hacc0[i] = 0.f; hacc1[i] = 0.f; }
        const int me = e - 1;
        const unsigned short* hbr = h_s[(e + 1) & 1];   // == h_s[(e-1)&1]

        if (e == 0) {
#pragma unroll
            for (int ks = 0; ks < 16; ++ks) G1STEP(ks);
        } else if (e < 32) {
#pragma unroll
            for (int ks = 0; ks < 16; ++ks) { G1STEP(ks); G2STEP(ks); }
        } else {
#pragma unroll
            for (int ks = 0; ks < 16; ++ks) G2STEP(ks);
        }

        // epilogue: +b1, relu, * gate weight, packed 8B -> h_s[e&1]
        if (e < 32) {
            unsigned short* hw = h_s[e & 1];
            const int rr = rl0 + l31;
            const float gw = gws[rr * 33 + e];
            const int rbase = rr << 8, rsw = rr & 7;
#pragma unroll
            for (int cg = 0; cg < 2; ++cg) {
                const f32x16* hp = cg ? (const f32x16*)&hacc1 : (const f32x16*)&hacc0;
#pragma unroll
                for (int q = 0; q < 4; ++q) {
                    float4 bv = *(const float4*)(bias1 + e * 256 +
                                                 (2 * p + cg) * 32 + q * 8 + hi * 4);
                    float v0 = fmaxf((*hp)[4 * q + 0] + bv.x, 0.f) * gw;
                    float v1 = fmaxf((*hp)[4 * q + 1] + bv.y, 0.f) * gw;
                    float v2 = fmaxf((*hp)[4 * q + 2] + bv.z, 0.f) * gw;
                    float v3 = fmaxf((*hp)[4 * q + 3] + bv.w, 0.f) * gw;
                    uint2 pk;
                    pk.x = pack_bf16x2(v0, v1);
                    pk.y = pack_bf16x2(v2, v3);
                    int ch = (2 * p + cg) * 4 + q;
                    *(uint2*)(&hw[rbase + ((ch ^ rsw) << 3) + hi * 4]) = pk;
                }
            }
        }

        // barrier with LDS-only drain: weight prefetches stay in flight
        asm volatile("s_waitcnt lgkmcnt(0)" ::: "memory");
        __builtin_amdgcn_s_barrier();
    }

    // ---- final store: out C frags -> out[batch][outcol] ----
#pragma unroll
    for (int q = 0; q < 4; ++q) {
        f32x4 s0 = {oacc0[4 * q + 0], oacc0[4 * q + 1],
                    oacc0[4 * q + 2], oacc0[4 * q + 3]};
        f32x4 s1 = {oacc1[4 * q + 0], oacc1[4 * q + 1],
                    oacc1[4 * q + 2], oacc1[4 * q + 3]};
        *(f32x4*)(out + (long)(row0 + rl0 + l31) * 256 +
                  (2 * p) * 32 + q * 8 + hi * 4) = s0;
        *(f32x4*)(out + (long)(row0 + rl0 + l31) * 256 +
                  (2 * p + 1) * 32 + q * 8 + hi * 4) = s1;
    }
}

// ------------------------------- launch ------------------------------------
extern "C" void kernel_launch(void* const* d_in, const int* in_sizes, int n_in,
                              void* d_out, int out_size, void* d_ws, size_t ws_size,
                              hipStream_t stream) {
    (void)in_sizes; (void)n_in; (void)out_size; (void)ws_size;
    const float* x  = (const float*)d_in[0];   // [16384,256]
    const float* W1 = (const float*)d_in[1];   // [32,256,256]
    const float* b1 = (const float*)d_in[2];   // [32,256]
    const float* W2 = (const float*)d_in[3];   // [32,256,256]
    const float* b2 = (const float*)d_in[4];   // [32,256]
    const float* Wg = (const float*)d_in[5];   // [32,256]
    const float* bg = (const float*)d_in[6];   // [32]
    float* out = (float*)d_out;                // [16384,256]

    // ws: Wr = 16 streams x 33 experts x 16 KB = 8.25 MiB (expert 32 = pad)
    unsigned short* Wr = (unsigned short*)d_ws;

    cvt_w<<<2048, 256, 0, stream>>>(W1, W2, Wr);
    moe_kernel<<<256, 512, 0, stream>>>(x, Wr, b1, b2, Wg, bg, out);
}

// Round 5
// 728.184 us; speedup vs baseline: 1.1443x; 1.0094x over previous
//
#include <hip/hip_runtime.h>
#include <hip/hip_bf16.h>

// ---------------------------------------------------------------------------
// MoE dense all-expert forward, MI355X / gfx950.  B=16384, D=H=O=256, E=32.
// Round 9: launch-bounds law fix (one-token change from R8).
//  EMPIRICAL LAW (R0/R1/R2/R4 triangulation): hipcc __launch_bounds__ 2nd arg
//  is min BLOCKS/CU (CUDA semantics). VGPR cap = 512/(waves/SIMD):
//    (512,2) -> 2 blk/CU -> 4 w/SIMD -> 128 cap (R4: need ~170 -> 600MB spill)
//    (1024,*) -> >=4 w/SIMD -> <=128 cap (R2/R3 spill catastrophes)
//    (512,1) -> 1 blk/CU -> 2 w/SIMD -> 256 cap  <- this round
//  Structure (unchanged from R8):
//  - 256 blocks x 512 thr. Wave = 64 out-cols x 32 rows; 2 col-streams share
//    one B-frag ds_read (0.5 KB LDS per 32KFLOP MFMA; LDS floor ~31 us).
//  - merged-role waves: GEMM1(e) + GEMM2(e-1) fused per k-step.
//  - 4 weight streams/wave, register rings depth 4 (~500 cyc prefetch cover).
//  - h_s double-buffered, ONE raw s_barrier per phase, lgkmcnt-only drain.
// ---------------------------------------------------------------------------

typedef __attribute__((ext_vector_type(8))) short bf16x8;   // 8 bf16 = 4 VGPRs
typedef __attribute__((ext_vector_type(4))) float f32x4;
typedef __attribute__((ext_vector_type(16))) float f32x16;  // 32x32 C frag

__device__ __forceinline__ unsigned short f2bf(float f) {
    unsigned u = __builtin_bit_cast(unsigned, f);
    u += 0x7FFFu + ((u >> 16) & 1u);        // round-to-nearest-even
    return (unsigned short)(u >> 16);
}
__device__ __forceinline__ unsigned pack_bf16x2(float a, float b) {
    return (unsigned)f2bf(a) | ((unsigned)f2bf(b) << 16);
}

// 16B-chunk XOR swizzle for [64 rows][256 elem] bf16 tiles (index in ushorts)
#define LX(r, ch) (((r) << 8) + ((((ch) ^ ((r) & 7))) << 3))

// ------------------- W f32 -> bf16 convert + tile reorder ------------------
// Stream s = m*8 + cg: m=0 -> W1 rows cg*32..+31, m=1 -> W2 rows cg*32..+31.
// Per stream: 33 experts (e=32 is prefetch-overrun pad) x 16 k-step chunks.
// Chunk = 512 bf16 = 1 KB, element (lane, j): row = cg*32 + (lane&31),
// k = ks*16 + (lane>>5)*8 + j  — the mfma_32x32x16 A-frag order.
__global__ __launch_bounds__(256) void cvt_w(const float* __restrict__ W1,
                                             const float* __restrict__ W2,
                                             unsigned short* __restrict__ Wr) {
    int T = blockIdx.x * 256 + threadIdx.x;          // 524288 threads
    int lane = T & 63, ks = (T >> 6) & 15, e = (T >> 10) & 31;
    int cg = (T >> 15) & 7, m = (T >> 18) & 1;
    int l31 = lane & 31, hi = lane >> 5;
    const float* src = (m ? W2 : W1) +
                       ((long)e * 256 + cg * 32 + l31) * 256 + ks * 16 + hi * 8;
    float4 v0 = ((const float4*)src)[0], v1 = ((const float4*)src)[1];
    uint4 o;
    o.x = pack_bf16x2(v0.x, v0.y); o.y = pack_bf16x2(v0.z, v0.w);
    o.z = pack_bf16x2(v1.x, v1.y); o.w = pack_bf16x2(v1.z, v1.w);
    long U = (((long)(m * 8 + cg) * 33 + e) * 16 + ks) * 64 + lane;
    ((uint4*)Wr)[U] = o;
}

// ------------------------------ fused MoE ----------------------------------
// One GEMM1 k-step: consume 2 W1 ring slots, refill +4 ahead, 1 shared
// B-frag ds_read, 2 MFMAs.
#define G1STEP(ks) do {                                                        \
    bf16x8 aA = r1a[(ks) & 3], aB = r1b[(ks) & 3];                             \
    r1a[(ks) & 3] = *(const bf16x8*)(w1a + (e * 16 + (ks) + 4) * 512);         \
    r1b[(ks) & 3] = *(const bf16x8*)(w1b + (e * 16 + (ks) + 4) * 512);         \
    bf16x8 xb = *(const bf16x8*)(&x_s[LX(rl0 + l31, (ks) * 2 + hi)]);          \
    __builtin_amdgcn_s_setprio(1);                                             \
    hacc0 = __builtin_amdgcn_mfma_f32_32x32x16_bf16(aA, xb, hacc0, 0, 0, 0);   \
    hacc1 = __builtin_amdgcn_mfma_f32_32x32x16_bf16(aB, xb, hacc1, 0, 0, 0);   \
    __builtin_amdgcn_s_setprio(0);                                             \
} while (0)

// One GEMM2 k-step: consume 2 W2 ring slots, refill, shared B-frag from
// h_s[(e-1)&1], 2 MFMAs.
#define G2STEP(ks) do {                                                        \
    bf16x8 aA = r2a[(ks) & 3], aB = r2b[(ks) & 3];                             \
    r2a[(ks) & 3] = *(const bf16x8*)(w2a + (me * 16 + (ks) + 4) * 512);        \
    r2b[(ks) & 3] = *(const bf16x8*)(w2b + (me * 16 + (ks) + 4) * 512);        \
    bf16x8 hb = *(const bf16x8*)(&hbr[LX(rl0 + l31, (ks) * 2 + hi)]);          \
    __builtin_amdgcn_s_setprio(1);                                             \
    oacc0 = __builtin_amdgcn_mfma_f32_32x32x16_bf16(aA, hb, oacc0, 0, 0, 0);   \
    oacc1 = __builtin_amdgcn_mfma_f32_32x32x16_bf16(aB, hb, oacc1, 0, 0, 0);   \
    __builtin_amdgcn_s_setprio(0);                                             \
} while (0)

__global__ __launch_bounds__(512, 1) void moe_kernel(
    const float* __restrict__ x,
    const unsigned short* __restrict__ Wr,
    const float* __restrict__ bias1,
    const float* __restrict__ b2,
    const float* __restrict__ Wg,
    const float* __restrict__ bg,
    float* __restrict__ out)
{
    __shared__ __align__(16) unsigned short x_s[64 * 256];      // 32 KB
    __shared__ __align__(16) unsigned short h_s[2][64 * 256];   // 64 KB dbuf
    __shared__ float gws[64 * 33];                              // gate weights

    const int tid  = threadIdx.x;
    const int wv   = tid >> 6, lane = tid & 63;
    const int l31  = lane & 31, hi = lane >> 5;
    const int p    = wv & 3;                    // col-pair: cols p*64..p*64+63
    const int rl0  = (wv >> 2) * 32;            // row group: rows rl0..rl0+31
    const int row0 = blockIdx.x * 64;

    // ---- stage x tile: f32 global -> bf16 LDS (swizzled) ----
#pragma unroll
    for (int c = 0; c < 4; ++c) {
        int chunk = tid + c * 512;              // 2048 chunks of 8 elems
        int r = chunk >> 5, ch = chunk & 31;
        const float4* s = (const float4*)(x + (long)(row0 + r) * 256 + ch * 8);
        float4 v0 = s[0], v1 = s[1];
        uint4 o;
        o.x = pack_bf16x2(v0.x, v0.y); o.y = pack_bf16x2(v0.z, v0.w);
        o.z = pack_bf16x2(v1.x, v1.y); o.w = pack_bf16x2(v1.z, v1.w);
        *(uint4*)(&x_s[LX(r, ch)]) = o;
    }

    // ---- inline gating: 8 rows per wave, all f32 (matches reference) ----
    {
        const int e32 = lane & 31, half = lane >> 5;
        const float4* wg4 = (const float4*)(Wg + e32 * 256 + half * 128);
        float bgv = bg[e32];
        for (int i = 0; i < 8; ++i) {
            int lr = wv * 8 + i;
            const float4* xr4 = (const float4*)(x + (long)(row0 + lr) * 256 + half * 128);
            float acc = 0.f;
#pragma unroll
            for (int tt = 0; tt < 32; ++tt) {
                float4 w = wg4[tt], xv = xr4[tt];
                acc = fmaf(w.x, xv.x, acc); acc = fmaf(w.y, xv.y, acc);
                acc = fmaf(w.z, xv.z, acc); acc = fmaf(w.w, xv.w, acc);
            }
            acc += __shfl_xor(acc, 32);
            float score = (acc + bgv) / 2.71828182845904523f;   // TEMP = e

            float m = score;
#pragma unroll
            for (int d = 16; d >= 1; d >>= 1) m = fmaxf(m, __shfl_xor(m, d));
            float p_ = expf(score - m);
            float ps = p_;
#pragma unroll
            for (int d = 16; d >= 1; d >>= 1) ps += __shfl_xor(ps, d);
            float prob = p_ / ps;

            int rank = 0;
#pragma unroll
            for (int j = 0; j < 32; ++j) {
                float pj = __shfl(prob, j);
                rank += (pj > prob || (pj == prob && j < e32)) ? 1 : 0;
            }
            float kept = (rank < 22) ? prob : 0.f;
            float wsum = kept;
#pragma unroll
            for (int d = 16; d >= 1; d >>= 1) wsum += __shfl_xor(wsum, d);
            float weight = kept / (wsum + 1e-8f);

            if (half == 0) gws[lr * 33 + e32] = weight;
        }
    }

    __syncthreads();   // x_s + gws ready

    // ---- weight stream bases (4 streams/wave) + depth-4 ring preload ----
    const unsigned short* w1a = Wr + (long)(2 * p)     * (33 * 16 * 512) + lane * 8;
    const unsigned short* w1b = Wr + (long)(2 * p + 1) * (33 * 16 * 512) + lane * 8;
    const unsigned short* w2a = Wr + (long)(8 + 2 * p)     * (33 * 16 * 512) + lane * 8;
    const unsigned short* w2b = Wr + (long)(8 + 2 * p + 1) * (33 * 16 * 512) + lane * 8;
    bf16x8 r1a[4], r1b[4], r2a[4], r2b[4];
#pragma unroll
    for (int t = 0; t < 4; ++t) {
        r1a[t] = *(const bf16x8*)(w1a + t * 512);
        r1b[t] = *(const bf16x8*)(w1b + t * 512);
        r2a[t] = *(const bf16x8*)(w2a + t * 512);
        r2b[t] = *(const bf16x8*)(w2b + t * 512);
    }

    // ---- oacc init = sum_e gw * b2 (in-register bias2 combine) ----
    // C frag: batch row = lane&31, out-col = (reg&3) + 8*(reg>>2) + 4*hi
    f32x16 oacc0, oacc1;
#pragma unroll
    for (int i = 0; i < 16; ++i) { oacc0[i] = 0.f; oacc1[i] = 0.f; }
    for (int ee = 0; ee < 32; ++ee) {
        float gv = gws[(rl0 + l31) * 33 + ee];
#pragma unroll
        for (int q = 0; q < 4; ++q) {
            float4 ba = *(const float4*)(b2 + ee * 256 + (2 * p) * 32 + q * 8 + hi * 4);
            float4 bb = *(const float4*)(b2 + ee * 256 + (2 * p + 1) * 32 + q * 8 + hi * 4);
            oacc0[4 * q + 0] = fmaf(gv, ba.x, oacc0[4 * q + 0]);
            oacc0[4 * q + 1] = fmaf(gv, ba.y, oacc0[4 * q + 1]);
            oacc0[4 * q + 2] = fmaf(gv, ba.z, oacc0[4 * q + 2]);
            oacc0[4 * q + 3] = fmaf(gv, ba.w, oacc0[4 * q + 3]);
            oacc1[4 * q + 0] = fmaf(gv, bb.x, oacc1[4 * q + 0]);
            oacc1[4 * q + 1] = fmaf(gv, bb.y, oacc1[4 * q + 1]);
            oacc1[4 * q + 2] = fmaf(gv, bb.z, oacc1[4 * q + 2]);
            oacc1[4 * q + 3] = fmaf(gv, bb.w, oacc1[4 * q + 3]);
        }
    }

    // ---- expert pipeline: per phase e, GEMM1(e) + GEMM2(e-1) fused ----
    for (int e = 0; e <= 32; ++e) {
        f32x16 hacc0, hacc1;
#pragma unroll
        for (int i = 0; i < 16; ++i) { hacc0[i] = 0.f; hacc1[i] = 0.f; }
        const int me = e - 1;
        const unsigned short* hbr = h_s[(e + 1) & 1];   // == h_s[(e-1)&1]

        if (e == 0) {
#pragma unroll
            for (int ks = 0; ks < 16; ++ks) G1STEP(ks);
        } else if (e < 32) {
#pragma unroll
            for (int ks = 0; ks < 16; ++ks) { G1STEP(ks); G2STEP(ks); }
        } else {
#pragma unroll
            for (int ks = 0; ks < 16; ++ks) G2STEP(ks);
        }

        // epilogue: +b1, relu, * gate weight, packed 8B -> h_s[e&1]
        if (e < 32) {
            unsigned short* hw = h_s[e & 1];
            const int rr = rl0 + l31;
            const float gw = gws[rr * 33 + e];
            const int rbase = rr << 8, rsw = rr & 7;
#pragma unroll
            for (int cg = 0; cg < 2; ++cg) {
                const f32x16* hp = cg ? (const f32x16*)&hacc1 : (const f32x16*)&hacc0;
#pragma unroll
                for (int q = 0; q < 4; ++q) {
                    float4 bv = *(const float4*)(bias1 + e * 256 +
                                                 (2 * p + cg) * 32 + q * 8 + hi * 4);
                    float v0 = fmaxf((*hp)[4 * q + 0] + bv.x, 0.f) * gw;
                    float v1 = fmaxf((*hp)[4 * q + 1] + bv.y, 0.f) * gw;
                    float v2 = fmaxf((*hp)[4 * q + 2] + bv.z, 0.f) * gw;
                    float v3 = fmaxf((*hp)[4 * q + 3] + bv.w, 0.f) * gw;
                    uint2 pk;
                    pk.x = pack_bf16x2(v0, v1);
                    pk.y = pack_bf16x2(v2, v3);
                    int ch = (2 * p + cg) * 4 + q;
                    *(uint2*)(&hw[rbase + ((ch ^ rsw) << 3) + hi * 4]) = pk;
                }
            }
        }

        // barrier with LDS-only drain: weight prefetches stay in flight
        asm volatile("s_waitcnt lgkmcnt(0)" ::: "memory");
        __builtin_amdgcn_s_barrier();
    }

    // ---- final store: out C frags -> out[batch][outcol] ----
#pragma unroll
    for (int q = 0; q < 4; ++q) {
        f32x4 s0 = {oacc0[4 * q + 0], oacc0[4 * q + 1],
                    oacc0[4 * q + 2], oacc0[4 * q + 3]};
        f32x4 s1 = {oacc1[4 * q + 0], oacc1[4 * q + 1],
                    oacc1[4 * q + 2], oacc1[4 * q + 3]};
        *(f32x4*)(out + (long)(row0 + rl0 + l31) * 256 +
                  (2 * p) * 32 + q * 8 + hi * 4) = s0;
        *(f32x4*)(out + (long)(row0 + rl0 + l31) * 256 +
                  (2 * p + 1) * 32 + q * 8 + hi * 4) = s1;
    }
}

// ------------------------------- launch ------------------------------------
extern "C" void kernel_launch(void* const* d_in, const int* in_sizes, int n_in,
                              void* d_out, int out_size, void* d_ws, size_t ws_size,
                              hipStream_t stream) {
    (void)in_sizes; (void)n_in; (void)out_size; (void)ws_size;
    const float* x  = (const float*)d_in[0];   // [16384,256]
    const float* W1 = (const float*)d_in[1];   // [32,256,256]
    const float* b1 = (const float*)d_in[2];   // [32,256]
    const float* W2 = (const float*)d_in[3];   // [32,256,256]
    const float* b2 = (const float*)d_in[4];   // [32,256]
    const float* Wg = (const float*)d_in[5];   // [32,256]
    const float* bg = (const float*)d_in[6];   // [32]
    float* out = (float*)d_out;                // [16384,256]

    // ws: Wr = 16 streams x 33 experts x 16 KB = 8.25 MiB (expert 32 = pad)
    unsigned short* Wr = (unsigned short*)d_ws;

    cvt_w<<<2048, 256, 0, stream>>>(W1, W2, Wr);
    moe_kernel<<<256, 512, 0, stream>>>(x, Wr, b1, b2, Wg, bg, out);
}

// Round 6
// 412.424 us; speedup vs baseline: 2.0204x; 1.7656x over previous
//
#include <hip/hip_runtime.h>
#include <hip/hip_bf16.h>

// ---------------------------------------------------------------------------
// MoE dense all-expert forward, MI355X / gfx950.  B=16384, D=H=O=256, E=32.
// Round 10: traffic-optimal crew structure (R0) + 32x32 MFMA + deep rings.
//  LESSON (R6-R9 post-mortem): merged-role 32-row wave tiles DOUBLE the
//  global weight stream (each stream read by 2 row-group waves): 4.3 GB vs
//  crew design's 2.15 GB -> cache-BW wall ~500us. Crew waves own 64 cols x
//  ALL 64 rows -> every weight byte fetched once per block.
//  - 256 blocks x 512 thr (8 waves, 2/SIMD, 1 block/CU by LDS).
//    crew0 (waves 0-3) = GEMM1(e); crew1 (waves 4-7) = GEMM2(e-1).
//  - mfma_32x32x16: wave tile 64 cols x 64 rows = 4 x f32x16 acc.
//    CREW-SHARED acc registers: crew0 re-zeroes per phase (hacc), crew1
//    accumulates across phases (oacc, bias2-initialized) -> 64 regs not 128.
//  - weight A-frags register-streamed, depth-4 rings (~1000 cyc cover; all
//    blocks march experts in lockstep -> live set ~512KB, L2-resident).
//  - h_s double-buffered -> ONE raw s_barrier per phase, lgkmcnt-only drain
//    (weight prefetches stay in flight across barriers).
// ---------------------------------------------------------------------------

typedef __attribute__((ext_vector_type(8))) short bf16x8;   // 8 bf16 = 4 VGPRs
typedef __attribute__((ext_vector_type(4))) float f32x4;
typedef __attribute__((ext_vector_type(16))) float f32x16;  // 32x32 C frag

__device__ __forceinline__ unsigned short f2bf(float f) {
    unsigned u = __builtin_bit_cast(unsigned, f);
    u += 0x7FFFu + ((u >> 16) & 1u);        // round-to-nearest-even
    return (unsigned short)(u >> 16);
}
__device__ __forceinline__ unsigned pack_bf16x2(float a, float b) {
    return (unsigned)f2bf(a) | ((unsigned)f2bf(b) << 16);
}

// 16B-chunk XOR swizzle for [64 rows][256 elem] bf16 tiles (index in ushorts)
#define LX(r, ch) (((r) << 8) + ((((ch) ^ ((r) & 7))) << 3))

// ------------------- W f32 -> bf16 convert + tile reorder ------------------
// Stream s = m*8 + cg: m=0 -> W1 rows cg*32..+31, m=1 -> W2 rows cg*32..+31.
// Per stream: 33 experts (e=32 is prefetch-overrun pad) x 16 k-step chunks.
// Chunk = 512 bf16 = 1 KB, element (lane, j): row = cg*32 + (lane&31),
// k = ks*16 + (lane>>5)*8 + j  — the mfma_32x32x16 A-frag order.
__global__ __launch_bounds__(256) void cvt_w(const float* __restrict__ W1,
                                             const float* __restrict__ W2,
                                             unsigned short* __restrict__ Wr) {
    int T = blockIdx.x * 256 + threadIdx.x;          // 524288 threads
    int lane = T & 63, ks = (T >> 6) & 15, e = (T >> 10) & 31;
    int cg = (T >> 15) & 7, m = (T >> 18) & 1;
    int l31 = lane & 31, hi = lane >> 5;
    const float* src = (m ? W2 : W1) +
                       ((long)e * 256 + cg * 32 + l31) * 256 + ks * 16 + hi * 8;
    float4 v0 = ((const float4*)src)[0], v1 = ((const float4*)src)[1];
    uint4 o;
    o.x = pack_bf16x2(v0.x, v0.y); o.y = pack_bf16x2(v0.z, v0.w);
    o.z = pack_bf16x2(v1.x, v1.y); o.w = pack_bf16x2(v1.z, v1.w);
    long U = (((long)(m * 8 + cg) * 33 + e) * 16 + ks) * 64 + lane;
    ((uint4*)Wr)[U] = o;
}

#define MFMA32(A, B, C) __builtin_amdgcn_mfma_f32_32x32x16_bf16(A, B, C, 0, 0, 0)

// One crew k-step: consume 2 ring slots (col-groups 2g, 2g+1), refill +4
// ahead, 2 shared B-frag ds_reads (row-groups 0,1), 4 MFMAs.
// cur = e - crew (expert whose weights this crew streams this phase).
#define CSTEP(ks, BUF) do {                                                    \
    bf16x8 a0 = ra[(ks) & 3], a1 = rb[(ks) & 3];                               \
    ra[(ks) & 3] = *(const bf16x8*)(wa + (cur * 16 + (ks) + 4) * 512);         \
    rb[(ks) & 3] = *(const bf16x8*)(wb + (cur * 16 + (ks) + 4) * 512);         \
    bf16x8 b0 = *(const bf16x8*)(&(BUF)[LX(l31,      (ks) * 2 + hi)]);         \
    bf16x8 b1 = *(const bf16x8*)(&(BUF)[LX(32 + l31, (ks) * 2 + hi)]);         \
    __builtin_amdgcn_s_setprio(1);                                             \
    acc00 = MFMA32(a0, b0, acc00);                                             \
    acc01 = MFMA32(a0, b1, acc01);                                             \
    acc10 = MFMA32(a1, b0, acc10);                                             \
    acc11 = MFMA32(a1, b1, acc11);                                             \
    __builtin_amdgcn_s_setprio(0);                                             \
} while (0)

// Epilogue for one (cg, rg) quadrant: +b1, relu, *gate, pack -> h_s[e&1]
#define EPI(ACC, CG, RG) do {                                                  \
    const int rr = (RG) * 32 + l31;                                            \
    const float gw = gws[rr * 33 + e];                                         \
    const int rbase = rr << 8, rsw = rr & 7;                                   \
    _Pragma("unroll")                                                          \
    for (int q = 0; q < 4; ++q) {                                              \
        float4 bv = *(const float4*)(bias1 + e * 256 +                         \
                                     (2 * g + (CG)) * 32 + q * 8 + hi * 4);    \
        float v0 = fmaxf(ACC[4 * q + 0] + bv.x, 0.f) * gw;                     \
        float v1 = fmaxf(ACC[4 * q + 1] + bv.y, 0.f) * gw;                     \
        float v2 = fmaxf(ACC[4 * q + 2] + bv.z, 0.f) * gw;                     \
        float v3 = fmaxf(ACC[4 * q + 3] + bv.w, 0.f) * gw;                     \
        uint2 pk;                                                              \
        pk.x = pack_bf16x2(v0, v1);                                            \
        pk.y = pack_bf16x2(v2, v3);                                            \
        int ch = (2 * g + (CG)) * 4 + q;                                       \
        *(uint2*)(&hw[rbase + ((ch ^ rsw) << 3) + hi * 4]) = pk;               \
    }                                                                          \
} while (0)

__global__ __launch_bounds__(512, 1) void moe_kernel(
    const float* __restrict__ x,
    const unsigned short* __restrict__ Wr,
    const float* __restrict__ bias1,
    const float* __restrict__ b2,
    const float* __restrict__ Wg,
    const float* __restrict__ bg,
    float* __restrict__ out)
{
    __shared__ __align__(16) unsigned short x_s[64 * 256];      // 32 KB
    __shared__ __align__(16) unsigned short h_s[2][64 * 256];   // 64 KB dbuf
    __shared__ float gws[64 * 33];                              // gate weights

    const int tid  = threadIdx.x;
    const int wv   = tid >> 6, lane = tid & 63;
    const int l31  = lane & 31, hi = lane >> 5;
    const int crew = wv >> 2;                   // 0 = GEMM1, 1 = GEMM2
    const int g    = wv & 3;                    // cols g*64 .. g*64+63
    const int row0 = blockIdx.x * 64;

    // ---- stage x tile: f32 global -> bf16 LDS (swizzled) ----
#pragma unroll
    for (int c = 0; c < 4; ++c) {
        int chunk = tid + c * 512;              // 2048 chunks of 8 elems
        int r = chunk >> 5, ch = chunk & 31;
        const float4* s = (const float4*)(x + (long)(row0 + r) * 256 + ch * 8);
        float4 v0 = s[0], v1 = s[1];
        uint4 o;
        o.x = pack_bf16x2(v0.x, v0.y); o.y = pack_bf16x2(v0.z, v0.w);
        o.z = pack_bf16x2(v1.x, v1.y); o.w = pack_bf16x2(v1.z, v1.w);
        *(uint4*)(&x_s[LX(r, ch)]) = o;
    }

    // ---- inline gating: 8 rows per wave, all f32 (matches reference) ----
    {
        const int e32 = lane & 31, half = lane >> 5;
        const float4* wg4 = (const float4*)(Wg + e32 * 256 + half * 128);
        float bgv = bg[e32];
        for (int i = 0; i < 8; ++i) {
            int lr = wv * 8 + i;
            const float4* xr4 = (const float4*)(x + (long)(row0 + lr) * 256 + half * 128);
            float acc = 0.f;
#pragma unroll
            for (int tt = 0; tt < 32; ++tt) {
                float4 w = wg4[tt], xv = xr4[tt];
                acc = fmaf(w.x, xv.x, acc); acc = fmaf(w.y, xv.y, acc);
                acc = fmaf(w.z, xv.z, acc); acc = fmaf(w.w, xv.w, acc);
            }
            acc += __shfl_xor(acc, 32);
            float score = (acc + bgv) / 2.71828182845904523f;   // TEMP = e

            float m = score;
#pragma unroll
            for (int d = 16; d >= 1; d >>= 1) m = fmaxf(m, __shfl_xor(m, d));
            float p_ = expf(score - m);
            float ps = p_;
#pragma unroll
            for (int d = 16; d >= 1; d >>= 1) ps += __shfl_xor(ps, d);
            float prob = p_ / ps;

            int rank = 0;
#pragma unroll
            for (int j = 0; j < 32; ++j) {
                float pj = __shfl(prob, j);
                rank += (pj > prob || (pj == prob && j < e32)) ? 1 : 0;
            }
            float kept = (rank < 22) ? prob : 0.f;
            float wsum = kept;
#pragma unroll
            for (int d = 16; d >= 1; d >>= 1) wsum += __shfl_xor(wsum, d);
            float weight = kept / (wsum + 1e-8f);

            if (half == 0) gws[lr * 33 + e32] = weight;
        }
    }

    __syncthreads();   // x_s + gws ready

    // ---- weight stream bases: crew0 -> W1 streams 2g,2g+1; crew1 -> W2 ----
    const unsigned short* wa =
        Wr + (long)(crew * 8 + 2 * g) * (33 * 16 * 512) + lane * 8;
    const unsigned short* wb =
        Wr + (long)(crew * 8 + 2 * g + 1) * (33 * 16 * 512) + lane * 8;
    bf16x8 ra[4], rb[4];
#pragma unroll
    for (int t = 0; t < 4; ++t) {               // expert-0 chunks of own stream
        ra[t] = *(const bf16x8*)(wa + t * 512);
        rb[t] = *(const bf16x8*)(wb + t * 512);
    }

    // ---- crew-shared accumulators ----
    // crew0: per-phase hacc (re-zeroed). crew1: persistent oacc, init bias2.
    f32x16 acc00, acc01, acc10, acc11;
#pragma unroll
    for (int i = 0; i < 16; ++i) {
        acc00[i] = 0.f; acc01[i] = 0.f; acc10[i] = 0.f; acc11[i] = 0.f;
    }
    if (crew == 1) {
        for (int ee = 0; ee < 32; ++ee) {
            float gv0 = gws[l31 * 33 + ee];
            float gv1 = gws[(32 + l31) * 33 + ee];
#pragma unroll
            for (int q = 0; q < 4; ++q) {
                float4 b0 = *(const float4*)(b2 + ee * 256 + (2 * g) * 32 + q * 8 + hi * 4);
                float4 b1 = *(const float4*)(b2 + ee * 256 + (2 * g + 1) * 32 + q * 8 + hi * 4);
                acc00[4 * q + 0] = fmaf(gv0, b0.x, acc00[4 * q + 0]);
                acc00[4 * q + 1] = fmaf(gv0, b0.y, acc00[4 * q + 1]);
                acc00[4 * q + 2] = fmaf(gv0, b0.z, acc00[4 * q + 2]);
                acc00[4 * q + 3] = fmaf(gv0, b0.w, acc00[4 * q + 3]);
                acc01[4 * q + 0] = fmaf(gv1, b0.x, acc01[4 * q + 0]);
                acc01[4 * q + 1] = fmaf(gv1, b0.y, acc01[4 * q + 1]);
                acc01[4 * q + 2] = fmaf(gv1, b0.z, acc01[4 * q + 2]);
                acc01[4 * q + 3] = fmaf(gv1, b0.w, acc01[4 * q + 3]);
                acc10[4 * q + 0] = fmaf(gv0, b1.x, acc10[4 * q + 0]);
                acc10[4 * q + 1] = fmaf(gv0, b1.y, acc10[4 * q + 1]);
                acc10[4 * q + 2] = fmaf(gv0, b1.z, acc10[4 * q + 2]);
                acc10[4 * q + 3] = fmaf(gv0, b1.w, acc10[4 * q + 3]);
                acc11[4 * q + 0] = fmaf(gv1, b1.x, acc11[4 * q + 0]);
                acc11[4 * q + 1] = fmaf(gv1, b1.y, acc11[4 * q + 1]);
                acc11[4 * q + 2] = fmaf(gv1, b1.z, acc11[4 * q + 2]);
                acc11[4 * q + 3] = fmaf(gv1, b1.w, acc11[4 * q + 3]);
            }
        }
    }

    // ---- expert pipeline: crew0 GEMM1(e), crew1 GEMM2(e-1), 1 barrier ----
    for (int e = 0; e <= 32; ++e) {
        const int cur = e - crew;               // expert this crew streams
        if (crew == 0) {
            if (e < 32) {
#pragma unroll
                for (int i = 0; i < 16; ++i) {  // re-zero per phase (hacc)
                    acc00[i] = 0.f; acc01[i] = 0.f; acc10[i] = 0.f; acc11[i] = 0.f;
                }
#pragma unroll
                for (int ks = 0; ks < 16; ++ks) CSTEP(ks, x_s);
                // epilogue: +b1, relu, *gate -> h_s[e&1]
                unsigned short* hw = h_s[e & 1];
                EPI(acc00, 0, 0);
                EPI(acc01, 0, 1);
                EPI(acc10, 1, 0);
                EPI(acc11, 1, 1);
            }
        } else {
            if (e >= 1) {
                const unsigned short* hbr = h_s[(e + 1) & 1];  // h(e-1)
#pragma unroll
                for (int ks = 0; ks < 16; ++ks) CSTEP(ks, hbr);
            }
        }

        // barrier with LDS-only drain: weight prefetches stay in flight
        asm volatile("s_waitcnt lgkmcnt(0)" ::: "memory");
        __builtin_amdgcn_s_barrier();
    }

    // ---- final store (crew1): out = acc quadrants ----
    if (crew == 1) {
#pragma unroll
        for (int q = 0; q < 4; ++q) {
            f32x4 s00 = {acc00[4 * q + 0], acc00[4 * q + 1],
                         acc00[4 * q + 2], acc00[4 * q + 3]};
            f32x4 s01 = {acc01[4 * q + 0], acc01[4 * q + 1],
                         acc01[4 * q + 2], acc01[4 * q + 3]};
            f32x4 s10 = {acc10[4 * q + 0], acc10[4 * q + 1],
                         acc10[4 * q + 2], acc10[4 * q + 3]};
            f32x4 s11 = {acc11[4 * q + 0], acc11[4 * q + 1],
                         acc11[4 * q + 2], acc11[4 * q + 3]};
            *(f32x4*)(out + (long)(row0 + l31) * 256 +
                      (2 * g) * 32 + q * 8 + hi * 4) = s00;
            *(f32x4*)(out + (long)(row0 + 32 + l31) * 256 +
                      (2 * g) * 32 + q * 8 + hi * 4) = s01;
            *(f32x4*)(out + (long)(row0 + l31) * 256 +
                      (2 * g + 1) * 32 + q * 8 + hi * 4) = s10;
            *(f32x4*)(out + (long)(row0 + 32 + l31) * 256 +
                      (2 * g + 1) * 32 + q * 8 + hi * 4) = s11;
        }
    }
}

// ------------------------------- launch ------------------------------------
extern "C" void kernel_launch(void* const* d_in, const int* in_sizes, int n_in,
                              void* d_out, int out_size, void* d_ws, size_t ws_size,
                              hipStream_t stream) {
    (void)in_sizes; (void)n_in; (void)out_size; (void)ws_size;
    const float* x  = (const float*)d_in[0];   // [16384,256]
    const float* W1 = (const float*)d_in[1];   // [32,256,256]
    const float* b1 = (const float*)d_in[2];   // [32,256]
    const float* W2 = (const float*)d_in[3];   // [32,256,256]
    const float* b2 = (const float*)d_in[4];   // [32,256]
    const float* Wg = (const float*)d_in[5];   // [32,256]
    const float* bg = (const float*)d_in[6];   // [32]
    float* out = (float*)d_out;                // [16384,256]

    // ws: Wr = 16 streams x 33 experts x 16 KB = 8.25 MiB (expert 32 = pad)
    unsigned short* Wr = (unsigned short*)d_ws;

    cvt_w<<<2048, 256, 0, stream>>>(W1, W2, Wr);
    moe_kernel<<<256, 512, 0, stream>>>(x, Wr, b1, b2, Wg, bg, out);
}

// Round 7
// 274.730 us; speedup vs baseline: 3.0331x; 1.5012x over previous
//
#include <hip/hip_runtime.h>
#include <hip/hip_bf16.h>

// ---------------------------------------------------------------------------
// MoE dense all-expert forward, MI355X / gfx950.  B=16384, D=H=O=256, E=32.
// Round 11: register-budget fix v3 (R10 structure kept).
//  R10 post-mortem: (512,1) launch bounds did NOT lift the 128-VGPR target;
//  ~200 MB scratch stores remained. Full 16-step unroll also hoisted ~16
//  64-bit refill addresses (offsets > 13-bit imm) = ~32 live VGPRs.
//  This round:
//   1) __attribute__((amdgpu_waves_per_eu(2,2))): clang-native directive to
//      allocate for 2 waves/SIMD -> 256 unified VGPR+AGPR budget.
//   2) k-loop as 4 groups x 4 static steps (#pragma unroll 1 outer) with
//      bumped stream pointers (pa += 2048/group; 0-3 KB offsets fold into
//      global-load imm) -> live addressing 8 regs instead of ~32.
//  Structure unchanged from R10: crew waves (crew0 GEMM1(e), crew1
//  GEMM2(e-1)), 64x64 wave tiles, every weight byte fetched once per block
//  (2.15 GB total, L2-resident lockstep stream), depth-4 rings, h_s dbuf,
//  one s_barrier/phase with lgkmcnt-only drain.
// ---------------------------------------------------------------------------

typedef __attribute__((ext_vector_type(8))) short bf16x8;   // 8 bf16 = 4 VGPRs
typedef __attribute__((ext_vector_type(4))) float f32x4;
typedef __attribute__((ext_vector_type(16))) float f32x16;  // 32x32 C frag

__device__ __forceinline__ unsigned short f2bf(float f) {
    unsigned u = __builtin_bit_cast(unsigned, f);
    u += 0x7FFFu + ((u >> 16) & 1u);        // round-to-nearest-even
    return (unsigned short)(u >> 16);
}
__device__ __forceinline__ unsigned pack_bf16x2(float a, float b) {
    return (unsigned)f2bf(a) | ((unsigned)f2bf(b) << 16);
}

// 16B-chunk XOR swizzle for [64 rows][256 elem] bf16 tiles (index in ushorts)
#define LX(r, ch) (((r) << 8) + ((((ch) ^ ((r) & 7))) << 3))

// ------------------- W f32 -> bf16 convert + tile reorder ------------------
// Stream s = m*8 + cg: m=0 -> W1 rows cg*32..+31, m=1 -> W2 rows cg*32..+31.
// Per stream: 33 experts (e=32 is prefetch-overrun pad) x 16 k-step chunks.
// Chunk = 512 bf16 = 1 KB, element (lane, j): row = cg*32 + (lane&31),
// k = ks*16 + (lane>>5)*8 + j  — the mfma_32x32x16 A-frag order.
__global__ __launch_bounds__(256) void cvt_w(const float* __restrict__ W1,
                                             const float* __restrict__ W2,
                                             unsigned short* __restrict__ Wr) {
    int T = blockIdx.x * 256 + threadIdx.x;          // 524288 threads
    int lane = T & 63, ks = (T >> 6) & 15, e = (T >> 10) & 31;
    int cg = (T >> 15) & 7, m = (T >> 18) & 1;
    int l31 = lane & 31, hi = lane >> 5;
    const float* src = (m ? W2 : W1) +
                       ((long)e * 256 + cg * 32 + l31) * 256 + ks * 16 + hi * 8;
    float4 v0 = ((const float4*)src)[0], v1 = ((const float4*)src)[1];
    uint4 o;
    o.x = pack_bf16x2(v0.x, v0.y); o.y = pack_bf16x2(v0.z, v0.w);
    o.z = pack_bf16x2(v1.x, v1.y); o.w = pack_bf16x2(v1.z, v1.w);
    long U = (((long)(m * 8 + cg) * 33 + e) * 16 + ks) * 64 + lane;
    ((uint4*)Wr)[U] = o;
}

#define MFMA32(A, B, C) __builtin_amdgcn_mfma_f32_32x32x16_bf16(A, B, C, 0, 0, 0)

// One k-step (static j in 0..3 within a group): consume ring slot j, refill
// from bumped pointers (imm-foldable 0-3KB offsets), 2 shared B-frag
// ds_reads, 4 MFMAs.  ck = g4*8 + hi (group's LDS chunk base).
#define CSTEPJ(j, BUF) do {                                                    \
    bf16x8 a0 = ra[j], a1 = rb[j];                                             \
    ra[j] = *(const bf16x8*)(pa + (j) * 512);                                  \
    rb[j] = *(const bf16x8*)(pb + (j) * 512);                                  \
    bf16x8 b0 = *(const bf16x8*)(&(BUF)[LX(l31,      ck + (j) * 2)]);          \
    bf16x8 b1 = *(const bf16x8*)(&(BUF)[LX(32 + l31, ck + (j) * 2)]);          \
    __builtin_amdgcn_s_setprio(1);                                             \
    acc00 = MFMA32(a0, b0, acc00);                                             \
    acc01 = MFMA32(a0, b1, acc01);                                             \
    acc10 = MFMA32(a1, b0, acc10);                                             \
    acc11 = MFMA32(a1, b1, acc11);                                             \
    __builtin_amdgcn_s_setprio(0);                                             \
} while (0)

// Epilogue for one (cg, rg) quadrant: +b1, relu, *gate, pack -> h_s[e&1]
#define EPI(ACC, CG, RG) do {                                                  \
    const int rr = (RG) * 32 + l31;                                            \
    const float gw = gws[rr * 33 + e];                                         \
    const int rbase = rr << 8, rsw = rr & 7;                                   \
    _Pragma("unroll")                                                          \
    for (int q = 0; q < 4; ++q) {                                              \
        float4 bv = *(const float4*)(bias1 + e * 256 +                         \
                                     (2 * g + (CG)) * 32 + q * 8 + hi * 4);    \
        float v0 = fmaxf(ACC[4 * q + 0] + bv.x, 0.f) * gw;                     \
        float v1 = fmaxf(ACC[4 * q + 1] + bv.y, 0.f) * gw;                     \
        float v2 = fmaxf(ACC[4 * q + 2] + bv.z, 0.f) * gw;                     \
        float v3 = fmaxf(ACC[4 * q + 3] + bv.w, 0.f) * gw;                     \
        uint2 pk;                                                              \
        pk.x = pack_bf16x2(v0, v1);                                            \
        pk.y = pack_bf16x2(v2, v3);                                            \
        int ch = (2 * g + (CG)) * 4 + q;                                       \
        *(uint2*)(&hw[rbase + ((ch ^ rsw) << 3) + hi * 4]) = pk;               \
    }                                                                          \
} while (0)

__global__ __launch_bounds__(512)
__attribute__((amdgpu_waves_per_eu(2, 2)))
void moe_kernel(
    const float* __restrict__ x,
    const unsigned short* __restrict__ Wr,
    const float* __restrict__ bias1,
    const float* __restrict__ b2,
    const float* __restrict__ Wg,
    const float* __restrict__ bg,
    float* __restrict__ out)
{
    __shared__ __align__(16) unsigned short x_s[64 * 256];      // 32 KB
    __shared__ __align__(16) unsigned short h_s[2][64 * 256];   // 64 KB dbuf
    __shared__ float gws[64 * 33];                              // gate weights

    const int tid  = threadIdx.x;
    const int wv   = tid >> 6, lane = tid & 63;
    const int l31  = lane & 31, hi = lane >> 5;
    const int crew = wv >> 2;                   // 0 = GEMM1, 1 = GEMM2
    const int g    = wv & 3;                    // cols g*64 .. g*64+63
    const int row0 = blockIdx.x * 64;

    // ---- stage x tile: f32 global -> bf16 LDS (swizzled) ----
#pragma unroll
    for (int c = 0; c < 4; ++c) {
        int chunk = tid + c * 512;              // 2048 chunks of 8 elems
        int r = chunk >> 5, ch = chunk & 31;
        const float4* s = (const float4*)(x + (long)(row0 + r) * 256 + ch * 8);
        float4 v0 = s[0], v1 = s[1];
        uint4 o;
        o.x = pack_bf16x2(v0.x, v0.y); o.y = pack_bf16x2(v0.z, v0.w);
        o.z = pack_bf16x2(v1.x, v1.y); o.w = pack_bf16x2(v1.z, v1.w);
        *(uint4*)(&x_s[LX(r, ch)]) = o;
    }

    // ---- inline gating: 8 rows per wave, all f32 (matches reference) ----
    {
        const int e32 = lane & 31, half = lane >> 5;
        const float4* wg4 = (const float4*)(Wg + e32 * 256 + half * 128);
        float bgv = bg[e32];
        for (int i = 0; i < 8; ++i) {
            int lr = wv * 8 + i;
            const float4* xr4 = (const float4*)(x + (long)(row0 + lr) * 256 + half * 128);
            float acc = 0.f;
#pragma unroll
            for (int tt = 0; tt < 32; ++tt) {
                float4 w = wg4[tt], xv = xr4[tt];
                acc = fmaf(w.x, xv.x, acc); acc = fmaf(w.y, xv.y, acc);
                acc = fmaf(w.z, xv.z, acc); acc = fmaf(w.w, xv.w, acc);
            }
            acc += __shfl_xor(acc, 32);
            float score = (acc + bgv) / 2.71828182845904523f;   // TEMP = e

            float m = score;
#pragma unroll
            for (int d = 16; d >= 1; d >>= 1) m = fmaxf(m, __shfl_xor(m, d));
            float p_ = expf(score - m);
            float ps = p_;
#pragma unroll
            for (int d = 16; d >= 1; d >>= 1) ps += __shfl_xor(ps, d);
            float prob = p_ / ps;

            int rank = 0;
#pragma unroll
            for (int j = 0; j < 32; ++j) {
                float pj = __shfl(prob, j);
                rank += (pj > prob || (pj == prob && j < e32)) ? 1 : 0;
            }
            float kept = (rank < 22) ? prob : 0.f;
            float wsum = kept;
#pragma unroll
            for (int d = 16; d >= 1; d >>= 1) wsum += __shfl_xor(wsum, d);
            float weight = kept / (wsum + 1e-8f);

            if (half == 0) gws[lr * 33 + e32] = weight;
        }
    }

    __syncthreads();   // x_s + gws ready

    // ---- weight stream bases: crew0 -> W1 streams 2g,2g+1; crew1 -> W2 ----
    const unsigned short* wa =
        Wr + (long)(crew * 8 + 2 * g) * (33 * 16 * 512) + lane * 8;
    const unsigned short* wb =
        Wr + (long)(crew * 8 + 2 * g + 1) * (33 * 16 * 512) + lane * 8;
    bf16x8 ra[4], rb[4];
#pragma unroll
    for (int t = 0; t < 4; ++t) {               // expert-0 chunks of own stream
        ra[t] = *(const bf16x8*)(wa + t * 512);
        rb[t] = *(const bf16x8*)(wb + t * 512);
    }

    // ---- crew-shared accumulators ----
    // crew0: per-phase hacc (re-zeroed). crew1: persistent oacc, init bias2.
    f32x16 acc00, acc01, acc10, acc11;
#pragma unroll
    for (int i = 0; i < 16; ++i) {
        acc00[i] = 0.f; acc01[i] = 0.f; acc10[i] = 0.f; acc11[i] = 0.f;
    }
    if (crew == 1) {
        for (int ee = 0; ee < 32; ++ee) {
            float gv0 = gws[l31 * 33 + ee];
            float gv1 = gws[(32 + l31) * 33 + ee];
#pragma unroll
            for (int q = 0; q < 4; ++q) {
                float4 b0 = *(const float4*)(b2 + ee * 256 + (2 * g) * 32 + q * 8 + hi * 4);
                float4 b1 = *(const float4*)(b2 + ee * 256 + (2 * g + 1) * 32 + q * 8 + hi * 4);
                acc00[4 * q + 0] = fmaf(gv0, b0.x, acc00[4 * q + 0]);
                acc00[4 * q + 1] = fmaf(gv0, b0.y, acc00[4 * q + 1]);
                acc00[4 * q + 2] = fmaf(gv0, b0.z, acc00[4 * q + 2]);
                acc00[4 * q + 3] = fmaf(gv0, b0.w, acc00[4 * q + 3]);
                acc01[4 * q + 0] = fmaf(gv1, b0.x, acc01[4 * q + 0]);
                acc01[4 * q + 1] = fmaf(gv1, b0.y, acc01[4 * q + 1]);
                acc01[4 * q + 2] = fmaf(gv1, b0.z, acc01[4 * q + 2]);
                acc01[4 * q + 3] = fmaf(gv1, b0.w, acc01[4 * q + 3]);
                acc10[4 * q + 0] = fmaf(gv0, b1.x, acc10[4 * q + 0]);
                acc10[4 * q + 1] = fmaf(gv0, b1.y, acc10[4 * q + 1]);
                acc10[4 * q + 2] = fmaf(gv0, b1.z, acc10[4 * q + 2]);
                acc10[4 * q + 3] = fmaf(gv0, b1.w, acc10[4 * q + 3]);
                acc11[4 * q + 0] = fmaf(gv1, b1.x, acc11[4 * q + 0]);
                acc11[4 * q + 1] = fmaf(gv1, b1.y, acc11[4 * q + 1]);
                acc11[4 * q + 2] = fmaf(gv1, b1.z, acc11[4 * q + 2]);
                acc11[4 * q + 3] = fmaf(gv1, b1.w, acc11[4 * q + 3]);
            }
        }
    }

    // ---- expert pipeline: crew0 GEMM1(e), crew1 GEMM2(e-1), 1 barrier ----
    for (int e = 0; e <= 32; ++e) {
        if (crew == 0) {
            if (e < 32) {
#pragma unroll
                for (int i = 0; i < 16; ++i) {  // re-zero per phase (hacc)
                    acc00[i] = 0.f; acc01[i] = 0.f; acc10[i] = 0.f; acc11[i] = 0.f;
                }
                const unsigned short* pa = wa + ((long)e * 16 + 4) * 512;
                const unsigned short* pb = wb + ((long)e * 16 + 4) * 512;
#pragma unroll 1
                for (int g4 = 0; g4 < 4; ++g4) {
                    const int ck = g4 * 8 + hi;
                    CSTEPJ(0, x_s); CSTEPJ(1, x_s);
                    CSTEPJ(2, x_s); CSTEPJ(3, x_s);
                    pa += 2048; pb += 2048;
                }
                // epilogue: +b1, relu, *gate -> h_s[e&1]
                unsigned short* hw = h_s[e & 1];
                EPI(acc00, 0, 0);
                EPI(acc01, 0, 1);
                EPI(acc10, 1, 0);
                EPI(acc11, 1, 1);
            }
        } else {
            if (e >= 1) {
                const unsigned short* hbr = h_s[(e + 1) & 1];  // h(e-1)
                const unsigned short* pa = wa + ((long)(e - 1) * 16 + 4) * 512;
                const unsigned short* pb = wb + ((long)(e - 1) * 16 + 4) * 512;
#pragma unroll 1
                for (int g4 = 0; g4 < 4; ++g4) {
                    const int ck = g4 * 8 + hi;
                    CSTEPJ(0, hbr); CSTEPJ(1, hbr);
                    CSTEPJ(2, hbr); CSTEPJ(3, hbr);
                    pa += 2048; pb += 2048;
                }
            }
        }

        // barrier with LDS-only drain: weight prefetches stay in flight
        asm volatile("s_waitcnt lgkmcnt(0)" ::: "memory");
        __builtin_amdgcn_s_barrier();
    }

    // ---- final store (crew1): out = acc quadrants ----
    if (crew == 1) {
#pragma unroll
        for (int q = 0; q < 4; ++q) {
            f32x4 s00 = {acc00[4 * q + 0], acc00[4 * q + 1],
                         acc00[4 * q + 2], acc00[4 * q + 3]};
            f32x4 s01 = {acc01[4 * q + 0], acc01[4 * q + 1],
                         acc01[4 * q + 2], acc01[4 * q + 3]};
            f32x4 s10 = {acc10[4 * q + 0], acc10[4 * q + 1],
                         acc10[4 * q + 2], acc10[4 * q + 3]};
            f32x4 s11 = {acc11[4 * q + 0], acc11[4 * q + 1],
                         acc11[4 * q + 2], acc11[4 * q + 3]};
            *(f32x4*)(out + (long)(row0 + l31) * 256 +
                      (2 * g) * 32 + q * 8 + hi * 4) = s00;
            *(f32x4*)(out + (long)(row0 + 32 + l31) * 256 +
                      (2 * g) * 32 + q * 8 + hi * 4) = s01;
            *(f32x4*)(out + (long)(row0 + l31) * 256 +
                      (2 * g + 1) * 32 + q * 8 + hi * 4) = s10;
            *(f32x4*)(out + (long)(row0 + 32 + l31) * 256 +
                      (2 * g + 1) * 32 + q * 8 + hi * 4) = s11;
        }
    }
}

// ------------------------------- launch ------------------------------------
extern "C" void kernel_launch(void* const* d_in, const int* in_sizes, int n_in,
                              void* d_out, int out_size, void* d_ws, size_t ws_size,
                              hipStream_t stream) {
    (void)in_sizes; (void)n_in; (void)out_size; (void)ws_size;
    const float* x  = (const float*)d_in[0];   // [16384,256]
    const float* W1 = (const float*)d_in[1];   // [32,256,256]
    const float* b1 = (const float*)d_in[2];   // [32,256]
    const float* W2 = (const float*)d_in[3];   // [32,256,256]
    const float* b2 = (const float*)d_in[4];   // [32,256]
    const float* Wg = (const float*)d_in[5];   // [32,256]
    const float* bg = (const float*)d_in[6];   // [32]
    float* out = (float*)d_out;                // [16384,256]

    // ws: Wr = 16 streams x 33 experts x 16 KB = 8.25 MiB (expert 32 = pad)
    unsigned short* Wr = (unsigned short*)d_ws;

    cvt_w<<<2048, 256, 0, stream>>>(W1, W2, Wr);
    moe_kernel<<<256, 512, 0, stream>>>(x, Wr, b1, b2, Wg, bg, out);
}

// Round 8
// 273.371 us; speedup vs baseline: 3.0481x; 1.0050x over previous
//
#include <hip/hip_runtime.h>
#include <hip/hip_bf16.h>

// ---------------------------------------------------------------------------
// MoE dense all-expert forward, MI355X / gfx950.  B=16384, D=H=O=256, E=32.
// Round 12: ILP deepening (R11 structure kept; R11 = 222us, 0 spills,
// MfmaUtil 26.7% = exactly the MFMA floor over a 73%-idle pipe).
//  With 2 waves/SIMD (grid=256=#CUs, 1 block/CU) latency hiding is ILP-only:
//   1) weight register rings depth 4 -> 8 (refill ~8 k-steps ahead);
//      static slot indices (rule #20), pointer bumps every 4 steps keep
//      global-load imm offsets in 0-3KB and avoid address hoisting.
//   2) B-frag +1-step software pipeline: MFMAs consume regs loaded last
//      step while this step prefetches next -> lgkm latency overlaps MFMA.
//      (Last-step over-read stays inside the 107KB LDS block; value unused.)
//  Unchanged: crew waves (crew0 GEMM1(e), crew1 GEMM2(e-1)), 64x64 tiles,
//  weights fetched once per block, h_s dbuf, one s_barrier/phase with
//  lgkmcnt-only drain, amdgpu_waves_per_eu(2,2) for the 256-reg budget.
// ---------------------------------------------------------------------------

typedef __attribute__((ext_vector_type(8))) short bf16x8;   // 8 bf16 = 4 VGPRs
typedef __attribute__((ext_vector_type(4))) float f32x4;
typedef __attribute__((ext_vector_type(16))) float f32x16;  // 32x32 C frag

__device__ __forceinline__ unsigned short f2bf(float f) {
    unsigned u = __builtin_bit_cast(unsigned, f);
    u += 0x7FFFu + ((u >> 16) & 1u);        // round-to-nearest-even
    return (unsigned short)(u >> 16);
}
__device__ __forceinline__ unsigned pack_bf16x2(float a, float b) {
    return (unsigned)f2bf(a) | ((unsigned)f2bf(b) << 16);
}

// 16B-chunk XOR swizzle for [64 rows][256 elem] bf16 tiles (index in ushorts)
#define LX(r, ch) (((r) << 8) + ((((ch) ^ ((r) & 7))) << 3))

// ------------------- W f32 -> bf16 convert + tile reorder ------------------
// Stream s = m*8 + cg: m=0 -> W1 rows cg*32..+31, m=1 -> W2 rows cg*32..+31.
// Per stream: 33 experts (e=32 is prefetch-overrun pad) x 16 k-step chunks.
// Chunk = 512 bf16 = 1 KB, element (lane, j): row = cg*32 + (lane&31),
// k = ks*16 + (lane>>5)*8 + j  — the mfma_32x32x16 A-frag order.
__global__ __launch_bounds__(256) void cvt_w(const float* __restrict__ W1,
                                             const float* __restrict__ W2,
                                             unsigned short* __restrict__ Wr) {
    int T = blockIdx.x * 256 + threadIdx.x;          // 524288 threads
    int lane = T & 63, ks = (T >> 6) & 15, e = (T >> 10) & 31;
    int cg = (T >> 15) & 7, m = (T >> 18) & 1;
    int l31 = lane & 31, hi = lane >> 5;
    const float* src = (m ? W2 : W1) +
                       ((long)e * 256 + cg * 32 + l31) * 256 + ks * 16 + hi * 8;
    float4 v0 = ((const float4*)src)[0], v1 = ((const float4*)src)[1];
    uint4 o;
    o.x = pack_bf16x2(v0.x, v0.y); o.y = pack_bf16x2(v0.z, v0.w);
    o.z = pack_bf16x2(v1.x, v1.y); o.w = pack_bf16x2(v1.z, v1.w);
    long U = (((long)(m * 8 + cg) * 33 + e) * 16 + ks) * 64 + lane;
    ((uint4*)Wr)[U] = o;
}

#define MFMA32(A, B, C) __builtin_amdgcn_mfma_f32_32x32x16_bf16(A, B, C, 0, 0, 0)

// One k-step (static j in 0..7 within a super-group): consume ring slot j
// (loaded 8 steps ago), refill it from the stream pointers (imm 0-3KB),
// prefetch next step's B-frags, 4 MFMAs on the CURRENT B-frags (cb0/cb1).
#define G8STEP(j, BUF) do {                                                    \
    bf16x8 a0 = ra[j], a1 = rb[j];                                             \
    ra[j] = *(const bf16x8*)(pla + ((j) & 3) * 512);                           \
    rb[j] = *(const bf16x8*)(plb + ((j) & 3) * 512);                           \
    bf16x8 nb0 = *(const bf16x8*)(&(BUF)[LX(l31,      ckn + (j) * 2 + 2)]);    \
    bf16x8 nb1 = *(const bf16x8*)(&(BUF)[LX(32 + l31, ckn + (j) * 2 + 2)]);    \
    __builtin_amdgcn_s_setprio(1);                                             \
    acc00 = MFMA32(a0, cb0, acc00);                                            \
    acc01 = MFMA32(a0, cb1, acc01);                                            \
    acc10 = MFMA32(a1, cb0, acc10);                                            \
    acc11 = MFMA32(a1, cb1, acc11);                                            \
    __builtin_amdgcn_s_setprio(0);                                             \
    cb0 = nb0; cb1 = nb1;                                                      \
    if (((j) & 3) == 3) { pla += 2048; plb += 2048; }                          \
} while (0)

// Epilogue for one (cg, rg) quadrant: +b1, relu, *gate, pack -> h_s[e&1]
#define EPI(ACC, CG, RG) do {                                                  \
    const int rr = (RG) * 32 + l31;                                            \
    const float gw = gws[rr * 33 + e];                                         \
    const int rbase = rr << 8, rsw = rr & 7;                                   \
    _Pragma("unroll")                                                          \
    for (int q = 0; q < 4; ++q) {                                              \
        float4 bv = *(const float4*)(bias1 + e * 256 +                         \
                                     (2 * g + (CG)) * 32 + q * 8 + hi * 4);    \
        float v0 = fmaxf(ACC[4 * q + 0] + bv.x, 0.f) * gw;                     \
        float v1 = fmaxf(ACC[4 * q + 1] + bv.y, 0.f) * gw;                     \
        float v2 = fmaxf(ACC[4 * q + 2] + bv.z, 0.f) * gw;                     \
        float v3 = fmaxf(ACC[4 * q + 3] + bv.w, 0.f) * gw;                     \
        uint2 pk;                                                              \
        pk.x = pack_bf16x2(v0, v1);                                            \
        pk.y = pack_bf16x2(v2, v3);                                            \
        int ch = (2 * g + (CG)) * 4 + q;                                       \
        *(uint2*)(&hw[rbase + ((ch ^ rsw) << 3) + hi * 4]) = pk;               \
    }                                                                          \
} while (0)

__global__ __launch_bounds__(512)
__attribute__((amdgpu_waves_per_eu(2, 2)))
void moe_kernel(
    const float* __restrict__ x,
    const unsigned short* __restrict__ Wr,
    const float* __restrict__ bias1,
    const float* __restrict__ b2,
    const float* __restrict__ Wg,
    const float* __restrict__ bg,
    float* __restrict__ out)
{
    __shared__ __align__(16) unsigned short x_s[64 * 256];      // 32 KB
    __shared__ __align__(16) unsigned short h_s[2][64 * 256];   // 64 KB dbuf
    __shared__ float gws[64 * 33];                              // gate weights

    const int tid  = threadIdx.x;
    const int wv   = tid >> 6, lane = tid & 63;
    const int l31  = lane & 31, hi = lane >> 5;
    const int crew = wv >> 2;                   // 0 = GEMM1, 1 = GEMM2
    const int g    = wv & 3;                    // cols g*64 .. g*64+63
    const int row0 = blockIdx.x * 64;

    // ---- stage x tile: f32 global -> bf16 LDS (swizzled) ----
#pragma unroll
    for (int c = 0; c < 4; ++c) {
        int chunk = tid + c * 512;              // 2048 chunks of 8 elems
        int r = chunk >> 5, ch = chunk & 31;
        const float4* s = (const float4*)(x + (long)(row0 + r) * 256 + ch * 8);
        float4 v0 = s[0], v1 = s[1];
        uint4 o;
        o.x = pack_bf16x2(v0.x, v0.y); o.y = pack_bf16x2(v0.z, v0.w);
        o.z = pack_bf16x2(v1.x, v1.y); o.w = pack_bf16x2(v1.z, v1.w);
        *(uint4*)(&x_s[LX(r, ch)]) = o;
    }

    // ---- inline gating: 8 rows per wave, all f32 (matches reference) ----
    {
        const int e32 = lane & 31, half = lane >> 5;
        const float4* wg4 = (const float4*)(Wg + e32 * 256 + half * 128);
        float bgv = bg[e32];
        for (int i = 0; i < 8; ++i) {
            int lr = wv * 8 + i;
            const float4* xr4 = (const float4*)(x + (long)(row0 + lr) * 256 + half * 128);
            float acc = 0.f;
#pragma unroll
            for (int tt = 0; tt < 32; ++tt) {
                float4 w = wg4[tt], xv = xr4[tt];
                acc = fmaf(w.x, xv.x, acc); acc = fmaf(w.y, xv.y, acc);
                acc = fmaf(w.z, xv.z, acc); acc = fmaf(w.w, xv.w, acc);
            }
            acc += __shfl_xor(acc, 32);
            float score = (acc + bgv) / 2.71828182845904523f;   // TEMP = e

            float m = score;
#pragma unroll
            for (int d = 16; d >= 1; d >>= 1) m = fmaxf(m, __shfl_xor(m, d));
            float p_ = expf(score - m);
            float ps = p_;
#pragma unroll
            for (int d = 16; d >= 1; d >>= 1) ps += __shfl_xor(ps, d);
            float prob = p_ / ps;

            int rank = 0;
#pragma unroll
            for (int j = 0; j < 32; ++j) {
                float pj = __shfl(prob, j);
                rank += (pj > prob || (pj == prob && j < e32)) ? 1 : 0;
            }
            float kept = (rank < 22) ? prob : 0.f;
            float wsum = kept;
#pragma unroll
            for (int d = 16; d >= 1; d >>= 1) wsum += __shfl_xor(wsum, d);
            float weight = kept / (wsum + 1e-8f);

            if (half == 0) gws[lr * 33 + e32] = weight;
        }
    }

    __syncthreads();   // x_s + gws ready

    // ---- weight streams: crew0 -> W1 (2g, 2g+1); crew1 -> W2.  Each crew's
    // consumption is CONTIGUOUS across experts, so one monotone load pointer
    // per stream suffices.  Depth-8 ring preload (chunks 0..7 of expert 0).
    const unsigned short* wa =
        Wr + (long)(crew * 8 + 2 * g) * (33 * 16 * 512) + lane * 8;
    const unsigned short* wb =
        Wr + (long)(crew * 8 + 2 * g + 1) * (33 * 16 * 512) + lane * 8;
    bf16x8 ra[8], rb[8];
#pragma unroll
    for (int t = 0; t < 8; ++t) {
        ra[t] = *(const bf16x8*)(wa + t * 512);
        rb[t] = *(const bf16x8*)(wb + t * 512);
    }
    const unsigned short* pla = wa + 8 * 512;   // next chunk to load (8 ahead)
    const unsigned short* plb = wb + 8 * 512;

    // ---- crew-shared accumulators ----
    // crew0: per-phase hacc (re-zeroed). crew1: persistent oacc, init bias2.
    f32x16 acc00, acc01, acc10, acc11;
#pragma unroll
    for (int i = 0; i < 16; ++i) {
        acc00[i] = 0.f; acc01[i] = 0.f; acc10[i] = 0.f; acc11[i] = 0.f;
    }
    if (crew == 1) {
        for (int ee = 0; ee < 32; ++ee) {
            float gv0 = gws[l31 * 33 + ee];
            float gv1 = gws[(32 + l31) * 33 + ee];
#pragma unroll
            for (int q = 0; q < 4; ++q) {
                float4 b0 = *(const float4*)(b2 + ee * 256 + (2 * g) * 32 + q * 8 + hi * 4);
                float4 b1 = *(const float4*)(b2 + ee * 256 + (2 * g + 1) * 32 + q * 8 + hi * 4);
                acc00[4 * q + 0] = fmaf(gv0, b0.x, acc00[4 * q + 0]);
                acc00[4 * q + 1] = fmaf(gv0, b0.y, acc00[4 * q + 1]);
                acc00[4 * q + 2] = fmaf(gv0, b0.z, acc00[4 * q + 2]);
                acc00[4 * q + 3] = fmaf(gv0, b0.w, acc00[4 * q + 3]);
                acc01[4 * q + 0] = fmaf(gv1, b0.x, acc01[4 * q + 0]);
                acc01[4 * q + 1] = fmaf(gv1, b0.y, acc01[4 * q + 1]);
                acc01[4 * q + 2] = fmaf(gv1, b0.z, acc01[4 * q + 2]);
                acc01[4 * q + 3] = fmaf(gv1, b0.w, acc01[4 * q + 3]);
                acc10[4 * q + 0] = fmaf(gv0, b1.x, acc10[4 * q + 0]);
                acc10[4 * q + 1] = fmaf(gv0, b1.y, acc10[4 * q + 1]);
                acc10[4 * q + 2] = fmaf(gv0, b1.z, acc10[4 * q + 2]);
                acc10[4 * q + 3] = fmaf(gv0, b1.w, acc10[4 * q + 3]);
                acc11[4 * q + 0] = fmaf(gv1, b1.x, acc11[4 * q + 0]);
                acc11[4 * q + 1] = fmaf(gv1, b1.y, acc11[4 * q + 1]);
                acc11[4 * q + 2] = fmaf(gv1, b1.z, acc11[4 * q + 2]);
                acc11[4 * q + 3] = fmaf(gv1, b1.w, acc11[4 * q + 3]);
            }
        }
    }

    // ---- expert pipeline: crew0 GEMM1(e), crew1 GEMM2(e-1), 1 barrier ----
#pragma unroll 1
    for (int e = 0; e <= 32; ++e) {
        if (crew == 0) {
            if (e < 32) {
#pragma unroll
                for (int i = 0; i < 16; ++i) {  // re-zero per phase (hacc)
                    acc00[i] = 0.f; acc01[i] = 0.f; acc10[i] = 0.f; acc11[i] = 0.f;
                }
                bf16x8 cb0 = *(const bf16x8*)(&x_s[LX(l31, hi)]);
                bf16x8 cb1 = *(const bf16x8*)(&x_s[LX(32 + l31, hi)]);
#pragma unroll 1
                for (int g8 = 0; g8 < 2; ++g8) {
                    const int ckn = g8 * 16 + hi;
                    G8STEP(0, x_s); G8STEP(1, x_s); G8STEP(2, x_s); G8STEP(3, x_s);
                    G8STEP(4, x_s); G8STEP(5, x_s); G8STEP(6, x_s); G8STEP(7, x_s);
                }
                // epilogue: +b1, relu, *gate -> h_s[e&1]
                unsigned short* hw = h_s[e & 1];
                EPI(acc00, 0, 0);
                EPI(acc01, 0, 1);
                EPI(acc10, 1, 0);
                EPI(acc11, 1, 1);
            }
        } else {
            if (e >= 1) {
                const unsigned short* hbr = h_s[(e + 1) & 1];  // h(e-1)
                bf16x8 cb0 = *(const bf16x8*)(&hbr[LX(l31, hi)]);
                bf16x8 cb1 = *(const bf16x8*)(&hbr[LX(32 + l31, hi)]);
#pragma unroll 1
                for (int g8 = 0; g8 < 2; ++g8) {
                    const int ckn = g8 * 16 + hi;
                    G8STEP(0, hbr); G8STEP(1, hbr); G8STEP(2, hbr); G8STEP(3, hbr);
                    G8STEP(4, hbr); G8STEP(5, hbr); G8STEP(6, hbr); G8STEP(7, hbr);
                }
            }
        }

        // barrier with LDS-only drain: weight prefetches stay in flight
        asm volatile("s_waitcnt lgkmcnt(0)" ::: "memory");
        __builtin_amdgcn_s_barrier();
    }

    // ---- final store (crew1): out = acc quadrants ----
    if (crew == 1) {
#pragma unroll
        for (int q = 0; q < 4; ++q) {
            f32x4 s00 = {acc00[4 * q + 0], acc00[4 * q + 1],
                         acc00[4 * q + 2], acc00[4 * q + 3]};
            f32x4 s01 = {acc01[4 * q + 0], acc01[4 * q + 1],
                         acc01[4 * q + 2], acc01[4 * q + 3]};
            f32x4 s10 = {acc10[4 * q + 0], acc10[4 * q + 1],
                         acc10[4 * q + 2], acc10[4 * q + 3]};
            f32x4 s11 = {acc11[4 * q + 0], acc11[4 * q + 1],
                         acc11[4 * q + 2], acc11[4 * q + 3]};
            *(f32x4*)(out + (long)(row0 + l31) * 256 +
                      (2 * g) * 32 + q * 8 + hi * 4) = s00;
            *(f32x4*)(out + (long)(row0 + 32 + l31) * 256 +
                      (2 * g) * 32 + q * 8 + hi * 4) = s01;
            *(f32x4*)(out + (long)(row0 + l31) * 256 +
                      (2 * g + 1) * 32 + q * 8 + hi * 4) = s10;
            *(f32x4*)(out + (long)(row0 + 32 + l31) * 256 +
                      (2 * g + 1) * 32 + q * 8 + hi * 4) = s11;
        }
    }
}

// ------------------------------- launch ------------------------------------
extern "C" void kernel_launch(void* const* d_in, const int* in_sizes, int n_in,
                              void* d_out, int out_size, void* d_ws, size_t ws_size,
                              hipStream_t stream) {
    (void)in_sizes; (void)n_in; (void)out_size; (void)ws_size;
    const float* x  = (const float*)d_in[0];   // [16384,256]
    const float* W1 = (const float*)d_in[1];   // [32,256,256]
    const float* b1 = (const float*)d_in[2];   // [32,256]
    const float* W2 = (const float*)d_in[3];   // [32,256,256]
    const float* b2 = (const float*)d_in[4];   // [32,256]
    const float* Wg = (const float*)d_in[5];   // [32,256]
    const float* bg = (const float*)d_in[6];   // [32]
    float* out = (float*)d_out;                // [16384,256]

    // ws: Wr = 16 streams x 33 experts x 16 KB = 8.25 MiB (expert 32 = pad)
    unsigned short* Wr = (unsigned short*)d_ws;

    cvt_w<<<2048, 256, 0, stream>>>(W1, W2, Wr);
    moe_kernel<<<256, 512, 0, stream>>>(x, Wr, b1, b2, Wg, bg, out);
}

// Round 9
// 272.015 us; speedup vs baseline: 3.0633x; 1.0050x over previous
//
#include <hip/hip_runtime.h>
#include <hip/hip_bf16.h>

// ---------------------------------------------------------------------------
// MoE dense all-expert forward, MI355X / gfx950.  B=16384, D=H=O=256, E=32.
// Round 13: 4-deep B-frag register ring (R12 structure kept).
//  R12 post-mortem: 211us, MfmaUtil 29.8%, VALUBusy 34.5%, 0 spills.
//  Per-step costs identified: (a) +1-step B pipeline exposes ~70cyc of
//  ds_read_b128 latency (120cyc vs ~50cyc of covering work); (b) the
//  cb0=nb0;cb1=nb1 pipeline copies = 8 v_mov/step (VALUBusy bloat).
//  Fix: cba[4]/cbb[4] register ring, fully static indices (rule #20):
//  step j consumes slot j&3 (loaded 4 steps ~300cyc earlier), refills it
//  for step j+4. No copies; latency covered. Phase prologue pre-reads 4
//  chunk-pairs; tail prefetches over-read harmlessly inside the LDS block
//  (values never consumed). A-ring depth 8 with 4-step pointer bumps
//  (imm offsets <= 1536, no address hoisting).
//  Unchanged: crew waves (crew0 GEMM1(e), crew1 GEMM2(e-1)), 64x64 tiles,
//  weights fetched once per block (~2.15 GB L2-resident lockstep), h_s
//  dbuf, one s_barrier/phase with lgkmcnt-only drain, waves_per_eu(2,2).
// ---------------------------------------------------------------------------

typedef __attribute__((ext_vector_type(8))) short bf16x8;   // 8 bf16 = 4 VGPRs
typedef __attribute__((ext_vector_type(4))) float f32x4;
typedef __attribute__((ext_vector_type(16))) float f32x16;  // 32x32 C frag

__device__ __forceinline__ unsigned short f2bf(float f) {
    unsigned u = __builtin_bit_cast(unsigned, f);
    u += 0x7FFFu + ((u >> 16) & 1u);        // round-to-nearest-even
    return (unsigned short)(u >> 16);
}
__device__ __forceinline__ unsigned pack_bf16x2(float a, float b) {
    return (unsigned)f2bf(a) | ((unsigned)f2bf(b) << 16);
}

// 16B-chunk XOR swizzle for [64 rows][256 elem] bf16 tiles (index in ushorts)
#define LX(r, ch) (((r) << 8) + ((((ch) ^ ((r) & 7))) << 3))

// ------------------- W f32 -> bf16 convert + tile reorder ------------------
// Stream s = m*8 + cg: m=0 -> W1 rows cg*32..+31, m=1 -> W2 rows cg*32..+31.
// Per stream: 33 experts (e=32 is prefetch-overrun pad) x 16 k-step chunks.
// Chunk = 512 bf16 = 1 KB, element (lane, j): row = cg*32 + (lane&31),
// k = ks*16 + (lane>>5)*8 + j  — the mfma_32x32x16 A-frag order.
__global__ __launch_bounds__(256) void cvt_w(const float* __restrict__ W1,
                                             const float* __restrict__ W2,
                                             unsigned short* __restrict__ Wr) {
    int T = blockIdx.x * 256 + threadIdx.x;          // 524288 threads
    int lane = T & 63, ks = (T >> 6) & 15, e = (T >> 10) & 31;
    int cg = (T >> 15) & 7, m = (T >> 18) & 1;
    int l31 = lane & 31, hi = lane >> 5;
    const float* src = (m ? W2 : W1) +
                       ((long)e * 256 + cg * 32 + l31) * 256 + ks * 16 + hi * 8;
    float4 v0 = ((const float4*)src)[0], v1 = ((const float4*)src)[1];
    uint4 o;
    o.x = pack_bf16x2(v0.x, v0.y); o.y = pack_bf16x2(v0.z, v0.w);
    o.z = pack_bf16x2(v1.x, v1.y); o.w = pack_bf16x2(v1.z, v1.w);
    long U = (((long)(m * 8 + cg) * 33 + e) * 16 + ks) * 64 + lane;
    ((uint4*)Wr)[U] = o;
}

#define MFMA32(A, B, C) __builtin_amdgcn_mfma_f32_32x32x16_bf16(A, B, C, 0, 0, 0)

// One k-step, static j in 0..7 within an 8-step group (global step = g8*8+j):
//  - consume A-ring slot j (depth 8), refill from bumped stream ptrs
//  - consume B-ring slot j&3 (loaded 4 steps ago), refill for step j+4
//  - 4 MFMAs
#define GSTEP(j, BUF) do {                                                     \
    bf16x8 a0 = ra[j], a1 = rb[j];                                             \
    ra[j] = *(const bf16x8*)(pla + ((j) & 3) * 512);                           \
    rb[j] = *(const bf16x8*)(plb + ((j) & 3) * 512);                           \
    bf16x8 b0 = cba[(j) & 3], b1 = cbb[(j) & 3];                               \
    cba[(j) & 3] = *(const bf16x8*)(&(BUF)[LX(l31,      ckn + ((j) + 4) * 2)]);\
    cbb[(j) & 3] = *(const bf16x8*)(&(BUF)[LX(32 + l31, ckn + ((j) + 4) * 2)]);\
    __builtin_amdgcn_s_setprio(1);                                             \
    acc00 = MFMA32(a0, b0, acc00);                                             \
    acc01 = MFMA32(a0, b1, acc01);                                             \
    acc10 = MFMA32(a1, b0, acc10);                                             \
    acc11 = MFMA32(a1, b1, acc11);                                             \
    __builtin_amdgcn_s_setprio(0);                                             \
    if (((j) & 3) == 3) { pla += 2048; plb += 2048; }                          \
} while (0)

// Epilogue for one (cg, rg) quadrant: +b1, relu, *gate, pack -> h_s[e&1]
#define EPI(ACC, CG, RG) do {                                                  \
    const int rr = (RG) * 32 + l31;                                            \
    const float gw = gws[rr * 33 + e];                                         \
    const int rbase = rr << 8, rsw = rr & 7;                                   \
    _Pragma("unroll")                                                          \
    for (int q = 0; q < 4; ++q) {                                              \
        float4 bv = *(const float4*)(bias1 + e * 256 +                         \
                                     (2 * g + (CG)) * 32 + q * 8 + hi * 4);    \
        float v0 = fmaxf(ACC[4 * q + 0] + bv.x, 0.f) * gw;                     \
        float v1 = fmaxf(ACC[4 * q + 1] + bv.y, 0.f) * gw;                     \
        float v2 = fmaxf(ACC[4 * q + 2] + bv.z, 0.f) * gw;                     \
        float v3 = fmaxf(ACC[4 * q + 3] + bv.w, 0.f) * gw;                     \
        uint2 pk;                                                              \
        pk.x = pack_bf16x2(v0, v1);                                            \
        pk.y = pack_bf16x2(v2, v3);                                            \
        int ch = (2 * g + (CG)) * 4 + q;                                       \
        *(uint2*)(&hw[rbase + ((ch ^ rsw) << 3) + hi * 4]) = pk;               \
    }                                                                          \
} while (0)

__global__ __launch_bounds__(512)
__attribute__((amdgpu_waves_per_eu(2, 2)))
void moe_kernel(
    const float* __restrict__ x,
    const unsigned short* __restrict__ Wr,
    const float* __restrict__ bias1,
    const float* __restrict__ b2,
    const float* __restrict__ Wg,
    const float* __restrict__ bg,
    float* __restrict__ out)
{
    __shared__ __align__(16) unsigned short x_s[64 * 256];      // 32 KB
    __shared__ __align__(16) unsigned short h_s[2][64 * 256];   // 64 KB dbuf
    __shared__ float gws[64 * 33];                              // gate weights

    const int tid  = threadIdx.x;
    const int wv   = tid >> 6, lane = tid & 63;
    const int l31  = lane & 31, hi = lane >> 5;
    const int crew = wv >> 2;                   // 0 = GEMM1, 1 = GEMM2
    const int g    = wv & 3;                    // cols g*64 .. g*64+63
    const int row0 = blockIdx.x * 64;

    // ---- stage x tile: f32 global -> bf16 LDS (swizzled) ----
#pragma unroll
    for (int c = 0; c < 4; ++c) {
        int chunk = tid + c * 512;              // 2048 chunks of 8 elems
        int r = chunk >> 5, ch = chunk & 31;
        const float4* s = (const float4*)(x + (long)(row0 + r) * 256 + ch * 8);
        float4 v0 = s[0], v1 = s[1];
        uint4 o;
        o.x = pack_bf16x2(v0.x, v0.y); o.y = pack_bf16x2(v0.z, v0.w);
        o.z = pack_bf16x2(v1.x, v1.y); o.w = pack_bf16x2(v1.z, v1.w);
        *(uint4*)(&x_s[LX(r, ch)]) = o;
    }

    // ---- inline gating: 8 rows per wave, all f32 (matches reference) ----
    {
        const int e32 = lane & 31, half = lane >> 5;
        const float4* wg4 = (const float4*)(Wg + e32 * 256 + half * 128);
        float bgv = bg[e32];
        for (int i = 0; i < 8; ++i) {
            int lr = wv * 8 + i;
            const float4* xr4 = (const float4*)(x + (long)(row0 + lr) * 256 + half * 128);
            float acc = 0.f;
#pragma unroll
            for (int tt = 0; tt < 32; ++tt) {
                float4 w = wg4[tt], xv = xr4[tt];
                acc = fmaf(w.x, xv.x, acc); acc = fmaf(w.y, xv.y, acc);
                acc = fmaf(w.z, xv.z, acc); acc = fmaf(w.w, xv.w, acc);
            }
            acc += __shfl_xor(acc, 32);
            float score = (acc + bgv) / 2.71828182845904523f;   // TEMP = e

            float m = score;
#pragma unroll
            for (int d = 16; d >= 1; d >>= 1) m = fmaxf(m, __shfl_xor(m, d));
            float p_ = expf(score - m);
            float ps = p_;
#pragma unroll
            for (int d = 16; d >= 1; d >>= 1) ps += __shfl_xor(ps, d);
            float prob = p_ / ps;

            int rank = 0;
#pragma unroll
            for (int j = 0; j < 32; ++j) {
                float pj = __shfl(prob, j);
                rank += (pj > prob || (pj == prob && j < e32)) ? 1 : 0;
            }
            float kept = (rank < 22) ? prob : 0.f;
            float wsum = kept;
#pragma unroll
            for (int d = 16; d >= 1; d >>= 1) wsum += __shfl_xor(wsum, d);
            float weight = kept / (wsum + 1e-8f);

            if (half == 0) gws[lr * 33 + e32] = weight;
        }
    }

    __syncthreads();   // x_s + gws ready

    // ---- weight streams: crew0 -> W1 (2g, 2g+1); crew1 -> W2.  Each crew's
    // consumption is CONTIGUOUS across experts; depth-8 ring preload.
    const unsigned short* wa =
        Wr + (long)(crew * 8 + 2 * g) * (33 * 16 * 512) + lane * 8;
    const unsigned short* wb =
        Wr + (long)(crew * 8 + 2 * g + 1) * (33 * 16 * 512) + lane * 8;
    bf16x8 ra[8], rb[8];
#pragma unroll
    for (int t = 0; t < 8; ++t) {
        ra[t] = *(const bf16x8*)(wa + t * 512);
        rb[t] = *(const bf16x8*)(wb + t * 512);
    }
    const unsigned short* pla = wa + 8 * 512;   // next chunk to load (8 ahead)
    const unsigned short* plb = wb + 8 * 512;

    // ---- B-frag register ring (depth 4, static indices) ----
    bf16x8 cba[4], cbb[4];

    // ---- crew-shared accumulators ----
    // crew0: per-phase hacc (re-zeroed). crew1: persistent oacc, init bias2.
    f32x16 acc00, acc01, acc10, acc11;
#pragma unroll
    for (int i = 0; i < 16; ++i) {
        acc00[i] = 0.f; acc01[i] = 0.f; acc10[i] = 0.f; acc11[i] = 0.f;
    }
    if (crew == 1) {
        for (int ee = 0; ee < 32; ++ee) {
            float gv0 = gws[l31 * 33 + ee];
            float gv1 = gws[(32 + l31) * 33 + ee];
#pragma unroll
            for (int q = 0; q < 4; ++q) {
                float4 b0 = *(const float4*)(b2 + ee * 256 + (2 * g) * 32 + q * 8 + hi * 4);
                float4 b1 = *(const float4*)(b2 + ee * 256 + (2 * g + 1) * 32 + q * 8 + hi * 4);
                acc00[4 * q + 0] = fmaf(gv0, b0.x, acc00[4 * q + 0]);
                acc00[4 * q + 1] = fmaf(gv0, b0.y, acc00[4 * q + 1]);
                acc00[4 * q + 2] = fmaf(gv0, b0.z, acc00[4 * q + 2]);
                acc00[4 * q + 3] = fmaf(gv0, b0.w, acc00[4 * q + 3]);
                acc01[4 * q + 0] = fmaf(gv1, b0.x, acc01[4 * q + 0]);
                acc01[4 * q + 1] = fmaf(gv1, b0.y, acc01[4 * q + 1]);
                acc01[4 * q + 2] = fmaf(gv1, b0.z, acc01[4 * q + 2]);
                acc01[4 * q + 3] = fmaf(gv1, b0.w, acc01[4 * q + 3]);
                acc10[4 * q + 0] = fmaf(gv0, b1.x, acc10[4 * q + 0]);
                acc10[4 * q + 1] = fmaf(gv0, b1.y, acc10[4 * q + 1]);
                acc10[4 * q + 2] = fmaf(gv0, b1.z, acc10[4 * q + 2]);
                acc10[4 * q + 3] = fmaf(gv0, b1.w, acc10[4 * q + 3]);
                acc11[4 * q + 0] = fmaf(gv1, b1.x, acc11[4 * q + 0]);
                acc11[4 * q + 1] = fmaf(gv1, b1.y, acc11[4 * q + 1]);
                acc11[4 * q + 2] = fmaf(gv1, b1.z, acc11[4 * q + 2]);
                acc11[4 * q + 3] = fmaf(gv1, b1.w, acc11[4 * q + 3]);
            }
        }
    }

    // ---- expert pipeline: crew0 GEMM1(e), crew1 GEMM2(e-1), 1 barrier ----
#pragma unroll 1
    for (int e = 0; e <= 32; ++e) {
        if (crew == 0) {
            if (e < 32) {
#pragma unroll
                for (int i = 0; i < 16; ++i) {  // re-zero per phase (hacc)
                    acc00[i] = 0.f; acc01[i] = 0.f; acc10[i] = 0.f; acc11[i] = 0.f;
                }
                // B-ring prologue: frags for steps 0..3
#pragma unroll
                for (int t = 0; t < 4; ++t) {
                    cba[t] = *(const bf16x8*)(&x_s[LX(l31,      t * 2 + hi)]);
                    cbb[t] = *(const bf16x8*)(&x_s[LX(32 + l31, t * 2 + hi)]);
                }
#pragma unroll 1
                for (int g8 = 0; g8 < 2; ++g8) {
                    const int ckn = g8 * 16 + hi;
                    GSTEP(0, x_s); GSTEP(1, x_s); GSTEP(2, x_s); GSTEP(3, x_s);
                    GSTEP(4, x_s); GSTEP(5, x_s); GSTEP(6, x_s); GSTEP(7, x_s);
                }
                // epilogue: +b1, relu, *gate -> h_s[e&1]
                unsigned short* hw = h_s[e & 1];
                EPI(acc00, 0, 0);
                EPI(acc01, 0, 1);
                EPI(acc10, 1, 0);
                EPI(acc11, 1, 1);
            }
        } else {
            if (e >= 1) {
                const unsigned short* hbr = h_s[(e + 1) & 1];  // h(e-1)
#pragma unroll
                for (int t = 0; t < 4; ++t) {
                    cba[t] = *(const bf16x8*)(&hbr[LX(l31,      t * 2 + hi)]);
                    cbb[t] = *(const bf16x8*)(&hbr[LX(32 + l31, t * 2 + hi)]);
                }
#pragma unroll 1
                for (int g8 = 0; g8 < 2; ++g8) {
                    const int ckn = g8 * 16 + hi;
                    GSTEP(0, hbr); GSTEP(1, hbr); GSTEP(2, hbr); GSTEP(3, hbr);
                    GSTEP(4, hbr); GSTEP(5, hbr); GSTEP(6, hbr); GSTEP(7, hbr);
                }
            }
        }

        // barrier with LDS-only drain: weight prefetches stay in flight
        asm volatile("s_waitcnt lgkmcnt(0)" ::: "memory");
        __builtin_amdgcn_s_barrier();
    }

    // ---- final store (crew1): out = acc quadrants ----
    if (crew == 1) {
#pragma unroll
        for (int q = 0; q < 4; ++q) {
            f32x4 s00 = {acc00[4 * q + 0], acc00[4 * q + 1],
                         acc00[4 * q + 2], acc00[4 * q + 3]};
            f32x4 s01 = {acc01[4 * q + 0], acc01[4 * q + 1],
                         acc01[4 * q + 2], acc01[4 * q + 3]};
            f32x4 s10 = {acc10[4 * q + 0], acc10[4 * q + 1],
                         acc10[4 * q + 2], acc10[4 * q + 3]};
            f32x4 s11 = {acc11[4 * q + 0], acc11[4 * q + 1],
                         acc11[4 * q + 2], acc11[4 * q + 3]};
            *(f32x4*)(out + (long)(row0 + l31) * 256 +
                      (2 * g) * 32 + q * 8 + hi * 4) = s00;
            *(f32x4*)(out + (long)(row0 + 32 + l31) * 256 +
                      (2 * g) * 32 + q * 8 + hi * 4) = s01;
            *(f32x4*)(out + (long)(row0 + l31) * 256 +
                      (2 * g + 1) * 32 + q * 8 + hi * 4) = s10;
            *(f32x4*)(out + (long)(row0 + 32 + l31) * 256 +
                      (2 * g + 1) * 32 + q * 8 + hi * 4) = s11;
        }
    }
}

// ------------------------------- launch ------------------------------------
extern "C" void kernel_launch(void* const* d_in, const int* in_sizes, int n_in,
                              void* d_out, int out_size, void* d_ws, size_t ws_size,
                              hipStream_t stream) {
    (void)in_sizes; (void)n_in; (void)out_size; (void)ws_size;
    const float* x  = (const float*)d_in[0];   // [16384,256]
    const float* W1 = (const float*)d_in[1];   // [32,256,256]
    const float* b1 = (const float*)d_in[2];   // [32,256]
    const float* W2 = (const float*)d_in[3];   // [32,256,256]
    const float* b2 = (const float*)d_in[4];   // [32,256]
    const float* Wg = (const float*)d_in[5];   // [32,256]
    const float* bg = (const float*)d_in[6];   // [32]
    float* out = (float*)d_out;                // [16384,256]

    // ws: Wr = 16 streams x 33 experts x 16 KB = 8.25 MiB (expert 32 = pad)
    unsigned short* Wr = (unsigned short*)d_ws;

    cvt_w<<<2048, 256, 0, stream>>>(W1, W2, Wr);
    moe_kernel<<<256, 512, 0, stream>>>(x, Wr, b1, b2, Wg, bg, out);
}